// Round 13
// baseline (250.488 us; speedup 1.0000x reference)
//
#include <hip/hip_runtime.h>
#include <hip/hip_bf16.h>

#define TQn 1024
#define NB  16
#define DIM 1024
#define BM  128
#define BN  128
#define BK  32
#define STR 40
#define VSTR 132

typedef __attribute__((ext_vector_type(4))) float f32x4;
typedef __attribute__((ext_vector_type(8))) short s16x8;
typedef __attribute__((ext_vector_type(4))) short s16x4;
typedef __attribute__((ext_vector_type(8))) _Float16 h16x8;

__device__ __forceinline__ short f2bf(float f){
  union { float f; unsigned u; } v; v.f = f;
  unsigned r = v.u + 0x7fffu + ((v.u >> 16) & 1u);  // RNE
  return (short)(r >> 16);
}
__device__ __forceinline__ float bf2f(short h){
  union { unsigned u; float f; } v; v.u = ((unsigned)(unsigned short)h) << 16;
  return v.f;
}
__device__ __forceinline__ short f2h(float f){
  _Float16 h = (_Float16)f;
  return __builtin_bit_cast(short, h);
}

__device__ __forceinline__ void gload16(const short* g, short* l){
#if __has_builtin(__builtin_amdgcn_global_load_lds)
  __builtin_amdgcn_global_load_lds(
      (const __attribute__((address_space(1))) unsigned int*)(const void*)g,
      (__attribute__((address_space(3))) unsigned int*)(void*)l, 16, 0, 0);
#else
  *reinterpret_cast<s16x8*>(l) = *reinterpret_cast<const s16x8*>(g);
#endif
}

// CH=2 (fp16 2-chain) and CH=4 (fp16 1-chain) use fp16 MFMA; CH=1/3 bf16.
template<int CH>
__device__ __forceinline__ f32x4 mfma_frag(s16x8 a, s16x8 b, f32x4 c){
  if constexpr (CH == 2 || CH == 4)
    return __builtin_amdgcn_mfma_f32_16x16x32_f16(
        __builtin_bit_cast(h16x8, a), __builtin_bit_cast(h16x8, b), c, 0, 0, 0);
  else
    return __builtin_amdgcn_mfma_f32_16x16x32_bf16(a, b, c, 0, 0, 0);
}

// ---------------- fast path ----------------

// merged fp32 -> fp16 conversion for query(16M) + keys(16M) + W(1M)
__global__ __launch_bounds__(256) void k0_cvtall(const float* __restrict__ q,
                                                 const float* __restrict__ k,
                                                 const float* __restrict__ wm,
                                                 short* __restrict__ qf,
                                                 short* __restrict__ kf,
                                                 short* __restrict__ wf){
  const size_t NQ = (size_t)16 * 1024 * 1024;
  const size_t i = ((size_t)blockIdx.x * 256 + threadIdx.x) * 4;
  const float* in; short* out; size_t off;
  if (i < NQ){ in = q; out = qf; off = i; }
  else if (i < 2 * NQ){ in = k; out = kf; off = i - NQ; }
  else { in = wm; out = wf; off = i - 2 * NQ; }
  f32x4 v = *reinterpret_cast<const f32x4*>(in + off);
  s16x4 o;
  #pragma unroll
  for (int j = 0; j < 4; ++j) o[j] = f2h(v[j]);
  *reinterpret_cast<s16x4*>(out + off) = o;
}

// values [b][s][v] fp32 -> vT [b][v][s] fp16
__global__ __launch_bounds__(256) void k0_vtrans(const float* __restrict__ vals,
                                                 short* __restrict__ vT){
  __shared__ short T[64 * 72];
  const int t = threadIdx.x;
  const int v0 = blockIdx.x * 64, s0 = blockIdx.y * 64, b = blockIdx.z;
  const int r16 = t >> 4, c4 = (t & 15) * 4;
  #pragma unroll
  for (int i = 0; i < 4; ++i){
    const int sl = i * 16 + r16;
    f32x4 v = *reinterpret_cast<const f32x4*>(vals + ((size_t)b * TQn + s0 + sl) * DIM + v0 + c4);
    #pragma unroll
    for (int j = 0; j < 4; ++j) T[(c4 + j) * 72 + sl] = f2h(v[j]);
  }
  __syncthreads();
  #pragma unroll
  for (int i = 0; i < 4; ++i){
    const int vl = i * 16 + r16;
    s16x4 o = *reinterpret_cast<const s16x4*>(&T[vl * 72 + c4]);
    *reinterpret_cast<s16x4*>(vT + ((size_t)b * DIM + v0 + vl) * TQn + s0 + c4) = o;
  }
}

// 256x256 A*B^T GEMM, 8 waves (2Mx4N), BK=64, dbuf 128KB, fragment-major
// (conflict-free b128), counted-vmcnt pipeline with extended wait distance:
// ALL 8 stage chunks of tile t+1 issued in ph0+ph1 of tile t (kk0 group then
// kk1 group); vmcnt(8) at end-ph1 (tile-t kk1: 4-phase flight) and vmcnt(4)
// at end-ph3 (t+1 kk0: 3-phase flight). Never drained mid-loop.
// CH=3: bf16 3x1024 ; CH=2: fp16 2x1024 ; CH=1: bf16 ; CH=4: fp16 plain
// EPI: 0 = fp32 C; 1 = bf16 hi/lo; 2 = fp16 hi/lo; 3 = fp16 single plane
template<int CH, int EPI>
__global__ __launch_bounds__(512, 2) void gemm256(
    const short* __restrict__ Ah, const short* __restrict__ Al,
    const short* __restrict__ Bh, const short* __restrict__ Bl,
    float* __restrict__ C, short* __restrict__ Ch, short* __restrict__ Cl,
    int ARS, int ABO, int BRS, int BBO, int CBO)
{
  constexpr int NSTEP = (CH == 3) ? 48 : (CH == 2) ? 32 : 16;
  __shared__ __align__(16) short lds[2 * 32768];   // 128 KB
  const int tid = threadIdx.x;
  const int lane = tid & 63, w = tid >> 6;
  const int cl = lane & 15, kg = lane >> 4;
  const int lane8 = lane * 8;
  const int bx = blockIdx.x, by = blockIdx.y, bz = blockIdx.z;
  const int wr = w >> 2, wc = w & 3;

  int aoffE[2], boffE[2], aldsE[2], bldsE[2];
  #pragma unroll
  for (int l = 0; l < 2; ++l){
    const int rg = 2 * w + l;
    const int arow = by * 256 + rg * 16 + cl;
    const int brow = bx * 256 + rg * 16 + cl;
    aoffE[l] = (arow * ARS + bz * ABO) * 1024 + kg * 8;
    boffE[l] = (brow * BRS + bz * BBO) * 1024 + kg * 8;
    aldsE[l] = (4 * w + 2 * l) * 512 + lane8;
    bldsE[l] = 16384 + (4 * w + 2 * l) * 512 + lane8;
  }

  f32x4 acc[8][4] = {};

  // prologue: stage tile 0 (chain 0 -> Ah,Bh) in deadline order (kk0 first).
  #pragma unroll
  for (int l = 0; l < 2; ++l) gload16(Bh + (size_t)boffE[l], &lds[bldsE[l]]);
  #pragma unroll
  for (int l = 0; l < 2; ++l) gload16(Ah + (size_t)aoffE[l], &lds[aldsE[l]]);
  #pragma unroll
  for (int l = 0; l < 2; ++l) gload16(Bh + (size_t)(boffE[l] + 32), &lds[bldsE[l] + 512]);
  #pragma unroll
  for (int l = 0; l < 2; ++l) gload16(Ah + (size_t)(aoffE[l] + 32), &lds[aldsE[l] + 512]);
  asm volatile("s_waitcnt vmcnt(4)" ::: "memory");   // tile0 kk0 landed; kk1 in flight
  __builtin_amdgcn_s_barrier();
  __builtin_amdgcn_sched_barrier(0);

  for (int t = 0; t < NSTEP; ++t){
    const int buf = (t & 1) * 32768;
    const int nbuf = buf ^ 32768;
    const bool pf = (t + 1 < NSTEP);
    int k1 = 0; const short *PA = Ah, *PB = Bh;
    if (pf){
      if (CH == 3){
        const int cc = (t + 1) % 3;
        k1 = ((t + 1) / 3) * 64;
        PA = (cc == 1) ? Al : Ah;
        PB = (cc == 2) ? Bl : Bh;
      } else if (CH == 2){
        k1 = ((t + 1) >> 1) * 64;
        PA = ((t + 1) & 1) ? Al : Ah;
        PB = Bh;
      } else k1 = (t + 1) * 64;
    }

    s16x8 av[4], bv[4];
    // ---- ph0: quad (m0-3, kk0); issue t+1 kk0 (B then A) ----
    #pragma unroll
    for (int m = 0; m < 4; ++m)
      av[m] = *reinterpret_cast<const s16x8*>(&lds[buf + ((wr * 8 + m) * 2 + 0) * 512 + lane8]);
    #pragma unroll
    for (int n = 0; n < 4; ++n)
      bv[n] = *reinterpret_cast<const s16x8*>(&lds[buf + 16384 + ((wc * 4 + n) * 2 + 0) * 512 + lane8]);
    if (pf){
      #pragma unroll
      for (int l = 0; l < 2; ++l) gload16(PB + (size_t)(boffE[l] + k1), &lds[nbuf + bldsE[l]]);
      #pragma unroll
      for (int l = 0; l < 2; ++l) gload16(PA + (size_t)(aoffE[l] + k1), &lds[nbuf + aldsE[l]]);
    }
    __builtin_amdgcn_s_barrier();
    __builtin_amdgcn_s_setprio(1);
    #pragma unroll
    for (int m = 0; m < 4; ++m)
      #pragma unroll
      for (int n = 0; n < 4; ++n)
        acc[m][n] = mfma_frag<CH>(av[m], bv[n], acc[m][n]);
    __builtin_amdgcn_s_setprio(0);
    __builtin_amdgcn_s_barrier();
    // ---- ph1: quad (m4-7, kk0), bv reused; issue t+1 kk1 (B then A) ----
    #pragma unroll
    for (int m = 0; m < 4; ++m)
      av[m] = *reinterpret_cast<const s16x8*>(&lds[buf + ((wr * 8 + 4 + m) * 2 + 0) * 512 + lane8]);
    if (pf){
      #pragma unroll
      for (int l = 0; l < 2; ++l) gload16(PB + (size_t)(boffE[l] + k1 + 32), &lds[nbuf + bldsE[l] + 512]);
      #pragma unroll
      for (int l = 0; l < 2; ++l) gload16(PA + (size_t)(aoffE[l] + k1 + 32), &lds[nbuf + aldsE[l] + 512]);
    }
    __builtin_amdgcn_s_barrier();
    __builtin_amdgcn_s_setprio(1);
    #pragma unroll
    for (int m = 0; m < 4; ++m)
      #pragma unroll
      for (int n = 0; n < 4; ++n)
        acc[4 + m][n] = mfma_frag<CH>(av[m], bv[n], acc[4 + m][n]);
    __builtin_amdgcn_s_setprio(0);
    // tile-t kk1 (issued ph0/ph1 of t-1, 4-phase flight) must be landed; t+1's 8 stay in flight
    if (pf) asm volatile("s_waitcnt vmcnt(8)" ::: "memory");
    else    asm volatile("s_waitcnt vmcnt(0)" ::: "memory");
    __builtin_amdgcn_s_barrier();
    __builtin_amdgcn_sched_barrier(0);
    // ---- ph2: quad (m0-3, kk1) ----
    #pragma unroll
    for (int m = 0; m < 4; ++m)
      av[m] = *reinterpret_cast<const s16x8*>(&lds[buf + ((wr * 8 + m) * 2 + 1) * 512 + lane8]);
    #pragma unroll
    for (int n = 0; n < 4; ++n)
      bv[n] = *reinterpret_cast<const s16x8*>(&lds[buf + 16384 + ((wc * 4 + n) * 2 + 1) * 512 + lane8]);
    __builtin_amdgcn_s_barrier();
    __builtin_amdgcn_s_setprio(1);
    #pragma unroll
    for (int m = 0; m < 4; ++m)
      #pragma unroll
      for (int n = 0; n < 4; ++n)
        acc[m][n] = mfma_frag<CH>(av[m], bv[n], acc[m][n]);
    __builtin_amdgcn_s_setprio(0);
    __builtin_amdgcn_s_barrier();
    // ---- ph3: quad (m4-7, kk1), bv reused ----
    #pragma unroll
    for (int m = 0; m < 4; ++m)
      av[m] = *reinterpret_cast<const s16x8*>(&lds[buf + ((wr * 8 + 4 + m) * 2 + 1) * 512 + lane8]);
    __builtin_amdgcn_s_barrier();
    __builtin_amdgcn_s_setprio(1);
    #pragma unroll
    for (int m = 0; m < 4; ++m)
      #pragma unroll
      for (int n = 0; n < 4; ++n)
        acc[4 + m][n] = mfma_frag<CH>(av[m], bv[n], acc[4 + m][n]);
    __builtin_amdgcn_s_setprio(0);
    if (pf){
      // t+1 kk0 (issued ph0, ~3-phase flight) landed; t+1 kk1 stays in flight
      asm volatile("s_waitcnt vmcnt(4)" ::: "memory");
      __builtin_amdgcn_s_barrier();
      __builtin_amdgcn_sched_barrier(0);
    }
  }

  #pragma unroll
  for (int m = 0; m < 8; ++m){
    const int row0 = by * 256 + wr * 128 + m * 16 + kg * 4;
    #pragma unroll
    for (int n = 0; n < 4; ++n){
      const int col = bx * 256 + wc * 64 + n * 16 + cl;
      #pragma unroll
      for (int j = 0; j < 4; ++j){
        const size_t off = ((size_t)(row0 + j) + (size_t)bz * CBO) * 1024 + col;
        if (EPI == 0) C[off] = acc[m][n][j];
        else if (EPI == 1){
          const float v = acc[m][n][j];
          const short hh = f2bf(v);
          Ch[off] = hh; Cl[off] = f2bf(v - bf2f(hh));
        } else if (EPI == 2){
          const float v = acc[m][n][j];
          const _Float16 hh = (_Float16)v;
          Ch[off] = __builtin_bit_cast(short, hh);
          const _Float16 ll = (_Float16)(v - (float)hh);
          Cl[off] = __builtin_bit_cast(short, ll);
        } else {
          Ch[off] = f2h(acc[m][n][j]);
        }
      }
    }
  }
}

// K3: in-place row softmax of (logits + mask[b][s]); optional fp16 copy for K4
__global__ __launch_bounds__(256) void k3_softmax(float* __restrict__ logits,
                                                  const float* __restrict__ mask,
                                                  short* __restrict__ sbf){
  const int row = blockIdx.x;       // b*TQ + t
  const int b = row >> 10;
  const int tid = threadIdx.x;
  float* p = logits + (size_t)row * DIM;
  f32x4 v  = *reinterpret_cast<const f32x4*>(p + tid * 4);
  f32x4 mk = *reinterpret_cast<const f32x4*>(mask + (size_t)b * DIM + tid * 4);
  v = v + mk;
  float mx = fmaxf(fmaxf(v[0], v[1]), fmaxf(v[2], v[3]));
  #pragma unroll
  for (int off = 32; off; off >>= 1) mx = fmaxf(mx, __shfl_xor(mx, off));
  __shared__ float red[8];
  const int lane = tid & 63, wid = tid >> 6;
  if (lane == 0) red[wid] = mx;
  __syncthreads();
  mx = fmaxf(fmaxf(red[0], red[1]), fmaxf(red[2], red[3]));
  f32x4 e;
  #pragma unroll
  for (int j = 0; j < 4; ++j) e[j] = __expf(v[j] - mx);
  float s = e[0] + e[1] + e[2] + e[3];
  #pragma unroll
  for (int off = 32; off; off >>= 1) s += __shfl_xor(s, off);
  if (lane == 0) red[4 + wid] = s;
  __syncthreads();
  s = red[4] + red[5] + red[6] + red[7];
  const float inv = 1.0f / s;
  f32x4 o;
  s16x4 ob;
  #pragma unroll
  for (int j = 0; j < 4; ++j){ o[j] = e[j] * inv; ob[j] = f2h(o[j]); }
  *reinterpret_cast<f32x4*>(p + tid * 4) = o;
  if (sbf) *reinterpret_cast<s16x4*>(sbf + (size_t)row * DIM + tid * 4) = ob;
}

// ---------------- fallback (round-3 passing) kernels ----------------

__global__ __launch_bounds__(256) void k1_qp(const float* __restrict__ A,
                                             const float* __restrict__ Wm,
                                             float* __restrict__ C){
  __shared__ __align__(16) short Ah[BM * STR];
  __shared__ __align__(16) short Al[BM * STR];
  __shared__ __align__(16) short Bh[BN * STR];
  __shared__ __align__(16) short Bl[BN * STR];
  const int tid = threadIdx.x;
  const int m0 = blockIdx.y * BM, n0 = blockIdx.x * BN;
  const int lane = tid & 63, wid = tid >> 6;
  const int wm = (wid >> 1) * 64, wn = (wid & 1) * 64;
  const int cl = lane & 15, kg = lane >> 4;
  const int rr = tid >> 3, f4 = (tid & 7) * 4;
  f32x4 acc[4][4] = {};
  for (int k0 = 0; k0 < DIM; k0 += BK){
    #pragma unroll
    for (int i = 0; i < 4; ++i){
      const int r = rr + i * 32;
      f32x4 va = *reinterpret_cast<const f32x4*>(A  + (size_t)(m0 + r) * DIM + k0 + f4);
      f32x4 vb = *reinterpret_cast<const f32x4*>(Wm + (size_t)(n0 + r) * DIM + k0 + f4);
      s16x4 ha, la, hb, lb;
      #pragma unroll
      for (int j = 0; j < 4; ++j){
        ha[j] = f2bf(va[j]); la[j] = f2bf(va[j] - bf2f(ha[j]));
        hb[j] = f2bf(vb[j]); lb[j] = f2bf(vb[j] - bf2f(hb[j]));
      }
      *reinterpret_cast<s16x4*>(&Ah[r * STR + f4]) = ha;
      *reinterpret_cast<s16x4*>(&Al[r * STR + f4]) = la;
      *reinterpret_cast<s16x4*>(&Bh[r * STR + f4]) = hb;
      *reinterpret_cast<s16x4*>(&Bl[r * STR + f4]) = lb;
    }
    __syncthreads();
    s16x8 ah[4], al8[4], bh8[4], bl8[4];
    #pragma unroll
    for (int m = 0; m < 4; ++m){
      ah[m]  = *reinterpret_cast<const s16x8*>(&Ah[(wm + m * 16 + cl) * STR + kg * 8]);
      al8[m] = *reinterpret_cast<const s16x8*>(&Al[(wm + m * 16 + cl) * STR + kg * 8]);
    }
    #pragma unroll
    for (int n = 0; n < 4; ++n){
      bh8[n] = *reinterpret_cast<const s16x8*>(&Bh[(wn + n * 16 + cl) * STR + kg * 8]);
      bl8[n] = *reinterpret_cast<const s16x8*>(&Bl[(wn + n * 16 + cl) * STR + kg * 8]);
    }
    #pragma unroll
    for (int m = 0; m < 4; ++m)
      #pragma unroll
      for (int n = 0; n < 4; ++n){
        acc[m][n] = __builtin_amdgcn_mfma_f32_16x16x32_bf16(ah[m],  bh8[n], acc[m][n], 0, 0, 0);
        acc[m][n] = __builtin_amdgcn_mfma_f32_16x16x32_bf16(al8[m], bh8[n], acc[m][n], 0, 0, 0);
        acc[m][n] = __builtin_amdgcn_mfma_f32_16x16x32_bf16(ah[m],  bl8[n], acc[m][n], 0, 0, 0);
      }
    __syncthreads();
  }
  #pragma unroll
  for (int m = 0; m < 4; ++m){
    const int row = m0 + wm + m * 16 + kg * 4;
    #pragma unroll
    for (int n = 0; n < 4; ++n){
      const int col = n0 + wn + n * 16 + cl;
      #pragma unroll
      for (int j = 0; j < 4; ++j)
        C[(size_t)(row + j) * DIM + col] = acc[m][n][j];
    }
  }
}

__global__ __launch_bounds__(256) void k2_logits(const float* __restrict__ qp,
                                                 const float* __restrict__ keys,
                                                 float* __restrict__ out){
  __shared__ __align__(16) short Ah[BM * STR];
  __shared__ __align__(16) short Al[BM * STR];
  __shared__ __align__(16) short Bh[BN * STR];
  __shared__ __align__(16) short Bl[BN * STR];
  const int tid = threadIdx.x;
  const int b = blockIdx.z;
  const int t0 = blockIdx.y * BM, s0 = blockIdx.x * BN;
  const int lane = tid & 63, wid = tid >> 6;
  const int wm = (wid >> 1) * 64, wn = (wid & 1) * 64;
  const int cl = lane & 15, kg = lane >> 4;
  const int rr = tid >> 3, f4 = (tid & 7) * 4;
  f32x4 acc[4][4] = {};
  for (int k0 = 0; k0 < DIM; k0 += BK){
    #pragma unroll
    for (int i = 0; i < 4; ++i){
      const int r = rr + i * 32;
      f32x4 va = *reinterpret_cast<const f32x4*>(qp   + (size_t)((t0 + r) * NB + b) * DIM + k0 + f4);
      f32x4 vb = *reinterpret_cast<const f32x4*>(keys + ((size_t)b * DIM + s0 + r) * DIM + k0 + f4);
      s16x4 ha, la, hb, lb;
      #pragma unroll
      for (int j = 0; j < 4; ++j){
        ha[j] = f2bf(va[j]); la[j] = f2bf(va[j] - bf2f(ha[j]));
        hb[j] = f2bf(vb[j]); lb[j] = f2bf(vb[j] - bf2f(hb[j]));
      }
      *reinterpret_cast<s16x4*>(&Ah[r * STR + f4]) = ha;
      *reinterpret_cast<s16x4*>(&Al[r * STR + f4]) = la;
      *reinterpret_cast<s16x4*>(&Bh[r * STR + f4]) = hb;
      *reinterpret_cast<s16x4*>(&Bl[r * STR + f4]) = lb;
    }
    __syncthreads();
    s16x8 ah[4], al8[4], bh8[4], bl8[4];
    #pragma unroll
    for (int m = 0; m < 4; ++m){
      ah[m]  = *reinterpret_cast<const s16x8*>(&Ah[(wm + m * 16 + cl) * STR + kg * 8]);
      al8[m] = *reinterpret_cast<const s16x8*>(&Al[(wm + m * 16 + cl) * STR + kg * 8]);
    }
    #pragma unroll
    for (int n = 0; n < 4; ++n){
      bh8[n] = *reinterpret_cast<const s16x8*>(&Bh[(wn + n * 16 + cl) * STR + kg * 8]);
      bl8[n] = *reinterpret_cast<const s16x8*>(&Bl[(wn + n * 16 + cl) * STR + kg * 8]);
    }
    #pragma unroll
    for (int m = 0; m < 4; ++m)
      #pragma unroll
      for (int n = 0; n < 4; ++n){
        acc[m][n] = __builtin_amdgcn_mfma_f32_16x16x32_bf16(ah[m],  bh8[n], acc[m][n], 0, 0, 0);
        acc[m][n] = __builtin_amdgcn_mfma_f32_16x16x32_bf16(al8[m], bh8[n], acc[m][n], 0, 0, 0);
        acc[m][n] = __builtin_amdgcn_mfma_f32_16x16x32_bf16(ah[m],  bl8[n], acc[m][n], 0, 0, 0);
      }
    __syncthreads();
  }
  #pragma unroll
  for (int m = 0; m < 4; ++m){
    const int trow = t0 + wm + m * 16 + kg * 4;
    #pragma unroll
    for (int n = 0; n < 4; ++n){
      const int scol = s0 + wn + n * 16 + cl;
      #pragma unroll
      for (int j = 0; j < 4; ++j)
        out[((size_t)b * TQn + trow + j) * DIM + scol] = acc[m][n][j];
    }
  }
}

__global__ __launch_bounds__(256) void k4_ctx(const float* __restrict__ score,
                                              const float* __restrict__ values,
                                              float* __restrict__ ctx){
  __shared__ __align__(16) short As[BM * STR];
  __shared__ __align__(16) float Vs[BK * VSTR];
  const int tid = threadIdx.x;
  const int b = blockIdx.z;
  const int t0 = blockIdx.y * BM, v0 = blockIdx.x * BN;
  const int lane = tid & 63, wid = tid >> 6;
  const int wm = (wid >> 1) * 64, wn = (wid & 1) * 64;
  const int cl = lane & 15, kg = lane >> 4;
  const int rr = tid >> 3, f4 = (tid & 7) * 4;
  const int vr = tid >> 5, vc = tid & 31;
  f32x4 acc[4][4] = {};
  for (int k0 = 0; k0 < DIM; k0 += BK){
    #pragma unroll
    for (int i = 0; i < 4; ++i){
      const int r = rr + i * 32;
      f32x4 va = *reinterpret_cast<const f32x4*>(score + ((size_t)b * TQn + t0 + r) * DIM + k0 + f4);
      s16x4 ha;
      #pragma unroll
      for (int j = 0; j < 4; ++j) ha[j] = f2bf(va[j]);
      *reinterpret_cast<s16x4*>(&As[r * STR + f4]) = ha;
      const int vrow = vr + i * 8;
      f32x4 vv = *reinterpret_cast<const f32x4*>(values + ((size_t)b * DIM + k0 + vrow) * DIM + v0 + vc * 4);
      const int cb = vc ^ (((vrow >> 3) & 1) << 2);
      *reinterpret_cast<f32x4*>(&Vs[vrow * VSTR + cb * 4]) = vv;
    }
    __syncthreads();
    s16x8 af[4], bfr[4];
    #pragma unroll
    for (int m = 0; m < 4; ++m)
      af[m] = *reinterpret_cast<const s16x8*>(&As[(wm + m * 16 + cl) * STR + kg * 8]);
    #pragma unroll
    for (int n = 0; n < 4; ++n){
      const int colb = wn + n * 16 + cl;
      const int cb = (colb >> 2) ^ ((kg & 1) << 2);
      #pragma unroll
      for (int j = 0; j < 8; ++j){
        const int rowv = kg * 8 + j;
        bfr[n][j] = f2bf(Vs[rowv * VSTR + cb * 4 + (colb & 3)]);
      }
    }
    #pragma unroll
    for (int m = 0; m < 4; ++m)
      #pragma unroll
      for (int n = 0; n < 4; ++n)
        acc[m][n] = __builtin_amdgcn_mfma_f32_16x16x32_bf16(af[m], bfr[n], acc[m][n], 0, 0, 0);
    __syncthreads();
  }
  #pragma unroll
  for (int m = 0; m < 4; ++m){
    const int trow = t0 + wm + m * 16 + kg * 4;
    #pragma unroll
    for (int n = 0; n < 4; ++n){
      const int vcol = v0 + wn + n * 16 + cl;
      #pragma unroll
      for (int j = 0; j < 4; ++j)
        ctx[((size_t)b * TQn + trow + j) * DIM + vcol] = acc[m][n][j];
    }
  }
}

extern "C" void kernel_launch(void* const* d_in, const int* in_sizes, int n_in,
                              void* d_out, int out_size, void* d_ws, size_t ws_size,
                              hipStream_t stream){
  (void)in_sizes; (void)n_in; (void)out_size;
  const float* query  = (const float*)d_in[0];  // [1024][16][1024] == m-major [16384][1024]
  const float* keys   = (const float*)d_in[1];  // [16][1024][1024]
  const float* values = (const float*)d_in[2];  // [16][1024][1024]
  const float* mask   = (const float*)d_in[3];  // [16][1024]
  const float* Wm     = (const float*)d_in[4];  // [1024][1024]
  float* score = (float*)d_out;                              // [16][1024][1024]
  float* ctx   = score + (size_t)NB * TQn * DIM;             // qp-plane scratch then real ctx
  dim3 blk(256, 1, 1);
  dim3 blk512(512, 1, 1);

  const size_t M16 = (size_t)16 * 1024 * 1024;   // 16M shorts
  const size_t M1  = (size_t)1024 * 1024;
  const size_t need = (4 * M16 + M1) * 2;        // 130 MB
  if (ws_size >= need){
    short* w  = (short*)d_ws;
    short* qf = w;                 // query fp16 (single plane)
    short* kf = qf + M16;          // keys fp16 (single plane)
    short* wf = kf + M16;          // W fp16 (single plane)
    short* vT = wf + M1;           // values^T fp16 [b][v][s]
    short* sb = vT + M16;          // score fp16
    short* qph = (short*)ctx;      // qp fp16 single plane (m-major [16384][1024])

    k0_cvtall<<<dim3(33792, 1, 1), blk, 0, stream>>>(query, keys, Wm, qf, kf, wf);
    k0_vtrans<<<dim3(16, 16, 16), blk, 0, stream>>>(values, vT);
    // K1: qp = qf . wf^T  (fp16 1-chain) -> fp16 single plane
    gemm256<4, 3><<<dim3(4, 64, 1), blk512, 0, stream>>>(qf, nullptr, wf, nullptr,
        nullptr, qph, nullptr, 1, 0, 1, 0, 0);
    // K2: logits = qph . kf  (fp16 1-chain)
    gemm256<4, 0><<<dim3(4, 4, 16), blk512, 0, stream>>>(qph, nullptr, kf, nullptr,
        score, nullptr, nullptr, 16, 1, 1, 1024, 1024);
    k3_softmax<<<dim3(NB * TQn, 1, 1), blk, 0, stream>>>(score, mask, sb);
    // K4: ctx = sb . vT  (fp16 1-chain)
    gemm256<4, 0><<<dim3(4, 4, 16), blk512, 0, stream>>>(sb, nullptr, vT, nullptr,
        ctx, nullptr, nullptr, 1, 1024, 1, 1024, 1024);
  } else {
    k1_qp<<<dim3(DIM / BN, (TQn * NB) / BM, 1), blk, 0, stream>>>(query, Wm, ctx);
    k2_logits<<<dim3(DIM / BN, TQn / BM, NB), blk, 0, stream>>>(ctx, keys, score);
    k3_softmax<<<dim3(NB * TQn, 1, 1), blk, 0, stream>>>(score, mask, nullptr);
    k4_ctx<<<dim3(DIM / BN, TQn / BM, NB), blk, 0, stream>>>(score, values, ctx);
  }
}

// Round 14
// 239.352 us; speedup vs baseline: 1.0465x; 1.0465x over previous
//
#include <hip/hip_runtime.h>
#include <hip/hip_bf16.h>

#define TQn 1024
#define NB  16
#define DIM 1024
#define BM  128
#define BN  128
#define BK  32
#define STR 40
#define VSTR 132

typedef __attribute__((ext_vector_type(4))) float f32x4;
typedef __attribute__((ext_vector_type(8))) short s16x8;
typedef __attribute__((ext_vector_type(4))) short s16x4;
typedef __attribute__((ext_vector_type(8))) _Float16 h16x8;

__device__ __forceinline__ short f2bf(float f){
  union { float f; unsigned u; } v; v.f = f;
  unsigned r = v.u + 0x7fffu + ((v.u >> 16) & 1u);  // RNE
  return (short)(r >> 16);
}
__device__ __forceinline__ float bf2f(short h){
  union { unsigned u; float f; } v; v.u = ((unsigned)(unsigned short)h) << 16;
  return v.f;
}
__device__ __forceinline__ short f2h(float f){
  _Float16 h = (_Float16)f;
  return __builtin_bit_cast(short, h);
}

__device__ __forceinline__ void gload16(const short* g, short* l){
#if __has_builtin(__builtin_amdgcn_global_load_lds)
  __builtin_amdgcn_global_load_lds(
      (const __attribute__((address_space(1))) unsigned int*)(const void*)g,
      (__attribute__((address_space(3))) unsigned int*)(void*)l, 16, 0, 0);
#else
  *reinterpret_cast<s16x8*>(l) = *reinterpret_cast<const s16x8*>(g);
#endif
}

// CH=2 (fp16 2-chain) and CH=4 (fp16 1-chain) use fp16 MFMA; CH=1/3 bf16.
template<int CH>
__device__ __forceinline__ f32x4 mfma_frag(s16x8 a, s16x8 b, f32x4 c){
  if constexpr (CH == 2 || CH == 4)
    return __builtin_amdgcn_mfma_f32_16x16x32_f16(
        __builtin_bit_cast(h16x8, a), __builtin_bit_cast(h16x8, b), c, 0, 0, 0);
  else
    return __builtin_amdgcn_mfma_f32_16x16x32_bf16(a, b, c, 0, 0, 0);
}

// ---------------- fast path ----------------

// fp32 -> single fp16 plane
__global__ __launch_bounds__(256) void k0_cvt16(const float* __restrict__ in,
                                                short* __restrict__ out){
  const size_t i = ((size_t)blockIdx.x * 256 + threadIdx.x) * 4;
  f32x4 v = *reinterpret_cast<const f32x4*>(in + i);
  s16x4 o;
  #pragma unroll
  for (int j = 0; j < 4; ++j) o[j] = f2h(v[j]);
  *reinterpret_cast<s16x4*>(out + i) = o;
}

// values [b][s][v] fp32 -> vT [b][v][s] fp16
__global__ __launch_bounds__(256) void k0_vtrans(const float* __restrict__ vals,
                                                 short* __restrict__ vT){
  __shared__ short T[64 * 72];
  const int t = threadIdx.x;
  const int v0 = blockIdx.x * 64, s0 = blockIdx.y * 64, b = blockIdx.z;
  const int r16 = t >> 4, c4 = (t & 15) * 4;
  #pragma unroll
  for (int i = 0; i < 4; ++i){
    const int sl = i * 16 + r16;
    f32x4 v = *reinterpret_cast<const f32x4*>(vals + ((size_t)b * TQn + s0 + sl) * DIM + v0 + c4);
    #pragma unroll
    for (int j = 0; j < 4; ++j) T[(c4 + j) * 72 + sl] = f2h(v[j]);
  }
  __syncthreads();
  #pragma unroll
  for (int i = 0; i < 4; ++i){
    const int vl = i * 16 + r16;
    s16x4 o = *reinterpret_cast<const s16x4*>(&T[vl * 72 + c4]);
    *reinterpret_cast<s16x4*>(vT + ((size_t)b * DIM + v0 + vl) * TQn + s0 + c4) = o;
  }
}

// 256x256 A*B^T GEMM, 8 waves (2Mx4N), BK=64, dbuf 128KB, fragment-major
// (conflict-free b128), r12 counted-vmcnt pipeline with MINIMAL barriers:
// only the two correctness barrier points per K-tile survive (mid-tile:
// publishes tile-t kk1 staged by all waves; end-tile: publishes t+1 kk0).
// All intra-phase scheduling barriers removed; setprio kept around MFMA.
// CH=3: bf16 3x1024 ; CH=2: fp16 2x1024 ; CH=1: bf16 ; CH=4: fp16 plain
// EPI: 0 = fp32 C; 1 = bf16 hi/lo; 2 = fp16 hi/lo; 3 = fp16 single plane
template<int CH, int EPI>
__global__ __launch_bounds__(512, 2) void gemm256(
    const short* __restrict__ Ah, const short* __restrict__ Al,
    const short* __restrict__ Bh, const short* __restrict__ Bl,
    float* __restrict__ C, short* __restrict__ Ch, short* __restrict__ Cl,
    int ARS, int ABO, int BRS, int BBO, int CBO)
{
  constexpr int NSTEP = (CH == 3) ? 48 : (CH == 2) ? 32 : 16;
  __shared__ __align__(16) short lds[2 * 32768];   // 128 KB
  const int tid = threadIdx.x;
  const int lane = tid & 63, w = tid >> 6;
  const int cl = lane & 15, kg = lane >> 4;
  const int lane8 = lane * 8;
  const int bx = blockIdx.x, by = blockIdx.y, bz = blockIdx.z;
  const int wr = w >> 2, wc = w & 3;

  int aoffE[2], boffE[2], aldsE[2], bldsE[2];
  #pragma unroll
  for (int l = 0; l < 2; ++l){
    const int rg = 2 * w + l;
    const int arow = by * 256 + rg * 16 + cl;
    const int brow = bx * 256 + rg * 16 + cl;
    aoffE[l] = (arow * ARS + bz * ABO) * 1024 + kg * 8;
    boffE[l] = (brow * BRS + bz * BBO) * 1024 + kg * 8;
    aldsE[l] = (4 * w + 2 * l) * 512 + lane8;
    bldsE[l] = 16384 + (4 * w + 2 * l) * 512 + lane8;
  }

  f32x4 acc[8][4] = {};

  // prologue: stage tile 0 (chain 0 -> Ah,Bh) in deadline order; kk1 stays in flight.
  #pragma unroll
  for (int l = 0; l < 2; ++l) gload16(Bh + (size_t)boffE[l], &lds[bldsE[l]]);
  #pragma unroll
  for (int l = 0; l < 2; ++l) gload16(Ah + (size_t)aoffE[l], &lds[aldsE[l]]);
  #pragma unroll
  for (int l = 0; l < 2; ++l) gload16(Bh + (size_t)(boffE[l] + 32), &lds[bldsE[l] + 512]);
  #pragma unroll
  for (int l = 0; l < 2; ++l) gload16(Ah + (size_t)(aoffE[l] + 32), &lds[aldsE[l] + 512]);
  asm volatile("s_waitcnt vmcnt(4)" ::: "memory");
  __builtin_amdgcn_s_barrier();
  __builtin_amdgcn_sched_barrier(0);

  for (int t = 0; t < NSTEP; ++t){
    const int buf = (t & 1) * 32768;
    const int nbuf = buf ^ 32768;
    const bool pf = (t + 1 < NSTEP);
    int k1 = 0; const short *PA = Ah, *PB = Bh;
    if (pf){
      if (CH == 3){
        const int cc = (t + 1) % 3;
        k1 = ((t + 1) / 3) * 64;
        PA = (cc == 1) ? Al : Ah;
        PB = (cc == 2) ? Bl : Bh;
      } else if (CH == 2){
        k1 = ((t + 1) >> 1) * 64;
        PA = ((t + 1) & 1) ? Al : Ah;
        PB = Bh;
      } else k1 = (t + 1) * 64;
    }

    s16x8 av[4], bv[4];
    // ---- ph0: quad (m0-3, kk0); issue t+1 B-kk0 ----
    #pragma unroll
    for (int m = 0; m < 4; ++m)
      av[m] = *reinterpret_cast<const s16x8*>(&lds[buf + ((wr * 8 + m) * 2 + 0) * 512 + lane8]);
    #pragma unroll
    for (int n = 0; n < 4; ++n)
      bv[n] = *reinterpret_cast<const s16x8*>(&lds[buf + 16384 + ((wc * 4 + n) * 2 + 0) * 512 + lane8]);
    if (pf){
      #pragma unroll
      for (int l = 0; l < 2; ++l) gload16(PB + (size_t)(boffE[l] + k1), &lds[nbuf + bldsE[l]]);
    }
    __builtin_amdgcn_s_setprio(1);
    #pragma unroll
    for (int m = 0; m < 4; ++m)
      #pragma unroll
      for (int n = 0; n < 4; ++n)
        acc[m][n] = mfma_frag<CH>(av[m], bv[n], acc[m][n]);
    __builtin_amdgcn_s_setprio(0);
    // ---- ph1: quad (m4-7, kk0), bv reused; issue t+1 A-kk0 ----
    #pragma unroll
    for (int m = 0; m < 4; ++m)
      av[m] = *reinterpret_cast<const s16x8*>(&lds[buf + ((wr * 8 + 4 + m) * 2 + 0) * 512 + lane8]);
    if (pf){
      #pragma unroll
      for (int l = 0; l < 2; ++l) gload16(PA + (size_t)(aoffE[l] + k1), &lds[nbuf + aldsE[l]]);
    }
    __builtin_amdgcn_s_setprio(1);
    #pragma unroll
    for (int m = 0; m < 4; ++m)
      #pragma unroll
      for (int n = 0; n < 4; ++n)
        acc[4 + m][n] = mfma_frag<CH>(av[m], bv[n], acc[4 + m][n]);
    __builtin_amdgcn_s_setprio(0);
    // correctness point 1: tile-t kk1 (all waves) must be resident before ph2 reads it
    if (pf) asm volatile("s_waitcnt vmcnt(4)" ::: "memory");
    else    asm volatile("s_waitcnt vmcnt(0)" ::: "memory");
    __builtin_amdgcn_s_barrier();
    __builtin_amdgcn_sched_barrier(0);
    // ---- ph2: quad (m0-3, kk1); issue t+1 B-kk1 ----
    #pragma unroll
    for (int m = 0; m < 4; ++m)
      av[m] = *reinterpret_cast<const s16x8*>(&lds[buf + ((wr * 8 + m) * 2 + 1) * 512 + lane8]);
    #pragma unroll
    for (int n = 0; n < 4; ++n)
      bv[n] = *reinterpret_cast<const s16x8*>(&lds[buf + 16384 + ((wc * 4 + n) * 2 + 1) * 512 + lane8]);
    if (pf){
      #pragma unroll
      for (int l = 0; l < 2; ++l) gload16(PB + (size_t)(boffE[l] + k1 + 32), &lds[nbuf + bldsE[l] + 512]);
    }
    __builtin_amdgcn_s_setprio(1);
    #pragma unroll
    for (int m = 0; m < 4; ++m)
      #pragma unroll
      for (int n = 0; n < 4; ++n)
        acc[m][n] = mfma_frag<CH>(av[m], bv[n], acc[m][n]);
    __builtin_amdgcn_s_setprio(0);
    // ---- ph3: quad (m4-7, kk1), bv reused; issue t+1 A-kk1 ----
    #pragma unroll
    for (int m = 0; m < 4; ++m)
      av[m] = *reinterpret_cast<const s16x8*>(&lds[buf + ((wr * 8 + 4 + m) * 2 + 1) * 512 + lane8]);
    if (pf){
      #pragma unroll
      for (int l = 0; l < 2; ++l) gload16(PA + (size_t)(aoffE[l] + k1 + 32), &lds[nbuf + aldsE[l] + 512]);
    }
    __builtin_amdgcn_s_setprio(1);
    #pragma unroll
    for (int m = 0; m < 4; ++m)
      #pragma unroll
      for (int n = 0; n < 4; ++n)
        acc[4 + m][n] = mfma_frag<CH>(av[m], bv[n], acc[4 + m][n]);
    __builtin_amdgcn_s_setprio(0);
    // correctness point 2: t+1 kk0 (all waves) resident before next tile's ph0
    if (pf){
      asm volatile("s_waitcnt vmcnt(4)" ::: "memory");
      __builtin_amdgcn_s_barrier();
      __builtin_amdgcn_sched_barrier(0);
    }
  }

  #pragma unroll
  for (int m = 0; m < 8; ++m){
    const int row0 = by * 256 + wr * 128 + m * 16 + kg * 4;
    #pragma unroll
    for (int n = 0; n < 4; ++n){
      const int col = bx * 256 + wc * 64 + n * 16 + cl;
      #pragma unroll
      for (int j = 0; j < 4; ++j){
        const size_t off = ((size_t)(row0 + j) + (size_t)bz * CBO) * 1024 + col;
        if (EPI == 0) C[off] = acc[m][n][j];
        else if (EPI == 1){
          const float v = acc[m][n][j];
          const short hh = f2bf(v);
          Ch[off] = hh; Cl[off] = f2bf(v - bf2f(hh));
        } else if (EPI == 2){
          const float v = acc[m][n][j];
          const _Float16 hh = (_Float16)v;
          Ch[off] = __builtin_bit_cast(short, hh);
          const _Float16 ll = (_Float16)(v - (float)hh);
          Cl[off] = __builtin_bit_cast(short, ll);
        } else {
          Ch[off] = f2h(acc[m][n][j]);
        }
      }
    }
  }
}

// K3: in-place row softmax of (logits + mask[b][s]); optional fp16 copy for K4
__global__ __launch_bounds__(256) void k3_softmax(float* __restrict__ logits,
                                                  const float* __restrict__ mask,
                                                  short* __restrict__ sbf){
  const int row = blockIdx.x;       // b*TQ + t
  const int b = row >> 10;
  const int tid = threadIdx.x;
  float* p = logits + (size_t)row * DIM;
  f32x4 v  = *reinterpret_cast<const f32x4*>(p + tid * 4);
  f32x4 mk = *reinterpret_cast<const f32x4*>(mask + (size_t)b * DIM + tid * 4);
  v = v + mk;
  float mx = fmaxf(fmaxf(v[0], v[1]), fmaxf(v[2], v[3]));
  #pragma unroll
  for (int off = 32; off; off >>= 1) mx = fmaxf(mx, __shfl_xor(mx, off));
  __shared__ float red[8];
  const int lane = tid & 63, wid = tid >> 6;
  if (lane == 0) red[wid] = mx;
  __syncthreads();
  mx = fmaxf(fmaxf(red[0], red[1]), fmaxf(red[2], red[3]));
  f32x4 e;
  #pragma unroll
  for (int j = 0; j < 4; ++j) e[j] = __expf(v[j] - mx);
  float s = e[0] + e[1] + e[2] + e[3];
  #pragma unroll
  for (int off = 32; off; off >>= 1) s += __shfl_xor(s, off);
  if (lane == 0) red[4 + wid] = s;
  __syncthreads();
  s = red[4] + red[5] + red[6] + red[7];
  const float inv = 1.0f / s;
  f32x4 o;
  s16x4 ob;
  #pragma unroll
  for (int j = 0; j < 4; ++j){ o[j] = e[j] * inv; ob[j] = f2h(o[j]); }
  *reinterpret_cast<f32x4*>(p + tid * 4) = o;
  if (sbf) *reinterpret_cast<s16x4*>(sbf + (size_t)row * DIM + tid * 4) = ob;
}

// ---------------- fallback (round-3 passing) kernels ----------------

__global__ __launch_bounds__(256) void k1_qp(const float* __restrict__ A,
                                             const float* __restrict__ Wm,
                                             float* __restrict__ C){
  __shared__ __align__(16) short Ah[BM * STR];
  __shared__ __align__(16) short Al[BM * STR];
  __shared__ __align__(16) short Bh[BN * STR];
  __shared__ __align__(16) short Bl[BN * STR];
  const int tid = threadIdx.x;
  const int m0 = blockIdx.y * BM, n0 = blockIdx.x * BN;
  const int lane = tid & 63, wid = tid >> 6;
  const int wm = (wid >> 1) * 64, wn = (wid & 1) * 64;
  const int cl = lane & 15, kg = lane >> 4;
  const int rr = tid >> 3, f4 = (tid & 7) * 4;
  f32x4 acc[4][4] = {};
  for (int k0 = 0; k0 < DIM; k0 += BK){
    #pragma unroll
    for (int i = 0; i < 4; ++i){
      const int r = rr + i * 32;
      f32x4 va = *reinterpret_cast<const f32x4*>(A  + (size_t)(m0 + r) * DIM + k0 + f4);
      f32x4 vb = *reinterpret_cast<const f32x4*>(Wm + (size_t)(n0 + r) * DIM + k0 + f4);
      s16x4 ha, la, hb, lb;
      #pragma unroll
      for (int j = 0; j < 4; ++j){
        ha[j] = f2bf(va[j]); la[j] = f2bf(va[j] - bf2f(ha[j]));
        hb[j] = f2bf(vb[j]); lb[j] = f2bf(vb[j] - bf2f(hb[j]));
      }
      *reinterpret_cast<s16x4*>(&Ah[r * STR + f4]) = ha;
      *reinterpret_cast<s16x4*>(&Al[r * STR + f4]) = la;
      *reinterpret_cast<s16x4*>(&Bh[r * STR + f4]) = hb;
      *reinterpret_cast<s16x4*>(&Bl[r * STR + f4]) = lb;
    }
    __syncthreads();
    s16x8 ah[4], al8[4], bh8[4], bl8[4];
    #pragma unroll
    for (int m = 0; m < 4; ++m){
      ah[m]  = *reinterpret_cast<const s16x8*>(&Ah[(wm + m * 16 + cl) * STR + kg * 8]);
      al8[m] = *reinterpret_cast<const s16x8*>(&Al[(wm + m * 16 + cl) * STR + kg * 8]);
    }
    #pragma unroll
    for (int n = 0; n < 4; ++n){
      bh8[n] = *reinterpret_cast<const s16x8*>(&Bh[(wn + n * 16 + cl) * STR + kg * 8]);
      bl8[n] = *reinterpret_cast<const s16x8*>(&Bl[(wn + n * 16 + cl) * STR + kg * 8]);
    }
    #pragma unroll
    for (int m = 0; m < 4; ++m)
      #pragma unroll
      for (int n = 0; n < 4; ++n){
        acc[m][n] = __builtin_amdgcn_mfma_f32_16x16x32_bf16(ah[m],  bh8[n], acc[m][n], 0, 0, 0);
        acc[m][n] = __builtin_amdgcn_mfma_f32_16x16x32_bf16(al8[m], bh8[n], acc[m][n], 0, 0, 0);
        acc[m][n] = __builtin_amdgcn_mfma_f32_16x16x32_bf16(ah[m],  bl8[n], acc[m][n], 0, 0, 0);
      }
    __syncthreads();
  }
  #pragma unroll
  for (int m = 0; m < 4; ++m){
    const int row = m0 + wm + m * 16 + kg * 4;
    #pragma unroll
    for (int n = 0; n < 4; ++n){
      const int col = n0 + wn + n * 16 + cl;
      #pragma unroll
      for (int j = 0; j < 4; ++j)
        C[(size_t)(row + j) * DIM + col] = acc[m][n][j];
    }
  }
}

__global__ __launch_bounds__(256) void k2_logits(const float* __restrict__ qp,
                                                 const float* __restrict__ keys,
                                                 float* __restrict__ out){
  __shared__ __align__(16) short Ah[BM * STR];
  __shared__ __align__(16) short Al[BM * STR];
  __shared__ __align__(16) short Bh[BN * STR];
  __shared__ __align__(16) short Bl[BN * STR];
  const int tid = threadIdx.x;
  const int b = blockIdx.z;
  const int t0 = blockIdx.y * BM, s0 = blockIdx.x * BN;
  const int lane = tid & 63, wid = tid >> 6;
  const int wm = (wid >> 1) * 64, wn = (wid & 1) * 64;
  const int cl = lane & 15, kg = lane >> 4;
  const int rr = tid >> 3, f4 = (tid & 7) * 4;
  f32x4 acc[4][4] = {};
  for (int k0 = 0; k0 < DIM; k0 += BK){
    #pragma unroll
    for (int i = 0; i < 4; ++i){
      const int r = rr + i * 32;
      f32x4 va = *reinterpret_cast<const f32x4*>(qp   + (size_t)((t0 + r) * NB + b) * DIM + k0 + f4);
      f32x4 vb = *reinterpret_cast<const f32x4*>(keys + ((size_t)b * DIM + s0 + r) * DIM + k0 + f4);
      s16x4 ha, la, hb, lb;
      #pragma unroll
      for (int j = 0; j < 4; ++j){
        ha[j] = f2bf(va[j]); la[j] = f2bf(va[j] - bf2f(ha[j]));
        hb[j] = f2bf(vb[j]); lb[j] = f2bf(vb[j] - bf2f(hb[j]));
      }
      *reinterpret_cast<s16x4*>(&Ah[r * STR + f4]) = ha;
      *reinterpret_cast<s16x4*>(&Al[r * STR + f4]) = la;
      *reinterpret_cast<s16x4*>(&Bh[r * STR + f4]) = hb;
      *reinterpret_cast<s16x4*>(&Bl[r * STR + f4]) = lb;
    }
    __syncthreads();
    s16x8 ah[4], al8[4], bh8[4], bl8[4];
    #pragma unroll
    for (int m = 0; m < 4; ++m){
      ah[m]  = *reinterpret_cast<const s16x8*>(&Ah[(wm + m * 16 + cl) * STR + kg * 8]);
      al8[m] = *reinterpret_cast<const s16x8*>(&Al[(wm + m * 16 + cl) * STR + kg * 8]);
    }
    #pragma unroll
    for (int n = 0; n < 4; ++n){
      bh8[n] = *reinterpret_cast<const s16x8*>(&Bh[(wn + n * 16 + cl) * STR + kg * 8]);
      bl8[n] = *reinterpret_cast<const s16x8*>(&Bl[(wn + n * 16 + cl) * STR + kg * 8]);
    }
    #pragma unroll
    for (int m = 0; m < 4; ++m)
      #pragma unroll
      for (int n = 0; n < 4; ++n){
        acc[m][n] = __builtin_amdgcn_mfma_f32_16x16x32_bf16(ah[m],  bh8[n], acc[m][n], 0, 0, 0);
        acc[m][n] = __builtin_amdgcn_mfma_f32_16x16x32_bf16(al8[m], bh8[n], acc[m][n], 0, 0, 0);
        acc[m][n] = __builtin_amdgcn_mfma_f32_16x16x32_bf16(ah[m],  bl8[n], acc[m][n], 0, 0, 0);
      }
    __syncthreads();
  }
  #pragma unroll
  for (int m = 0; m < 4; ++m){
    const int trow = t0 + wm + m * 16 + kg * 4;
    #pragma unroll
    for (int n = 0; n < 4; ++n){
      const int scol = s0 + wn + n * 16 + cl;
      #pragma unroll
      for (int j = 0; j < 4; ++j)
        out[((size_t)b * TQn + trow + j) * DIM + scol] = acc[m][n][j];
    }
  }
}

__global__ __launch_bounds__(256) void k4_ctx(const float* __restrict__ score,
                                              const float* __restrict__ values,
                                              float* __restrict__ ctx){
  __shared__ __align__(16) short As[BM * STR];
  __shared__ __align__(16) float Vs[BK * VSTR];
  const int tid = threadIdx.x;
  const int b = blockIdx.z;
  const int t0 = blockIdx.y * BM, v0 = blockIdx.x * BN;
  const int lane = tid & 63, wid = tid >> 6;
  const int wm = (wid >> 1) * 64, wn = (wid & 1) * 64;
  const int cl = lane & 15, kg = lane >> 4;
  const int rr = tid >> 3, f4 = (tid & 7) * 4;
  const int vr = tid >> 5, vc = tid & 31;
  f32x4 acc[4][4] = {};
  for (int k0 = 0; k0 < DIM; k0 += BK){
    #pragma unroll
    for (int i = 0; i < 4; ++i){
      const int r = rr + i * 32;
      f32x4 va = *reinterpret_cast<const f32x4*>(score + ((size_t)b * TQn + t0 + r) * DIM + k0 + f4);
      s16x4 ha;
      #pragma unroll
      for (int j = 0; j < 4; ++j) ha[j] = f2bf(va[j]);
      *reinterpret_cast<s16x4*>(&As[r * STR + f4]) = ha;
      const int vrow = vr + i * 8;
      f32x4 vv = *reinterpret_cast<const f32x4*>(values + ((size_t)b * DIM + k0 + vrow) * DIM + v0 + vc * 4);
      const int cb = vc ^ (((vrow >> 3) & 1) << 2);
      *reinterpret_cast<f32x4*>(&Vs[vrow * VSTR + cb * 4]) = vv;
    }
    __syncthreads();
    s16x8 af[4], bfr[4];
    #pragma unroll
    for (int m = 0; m < 4; ++m)
      af[m] = *reinterpret_cast<const s16x8*>(&As[(wm + m * 16 + cl) * STR + kg * 8]);
    #pragma unroll
    for (int n = 0; n < 4; ++n){
      const int colb = wn + n * 16 + cl;
      const int cb = (colb >> 2) ^ ((kg & 1) << 2);
      #pragma unroll
      for (int j = 0; j < 8; ++j){
        const int rowv = kg * 8 + j;
        bfr[n][j] = f2bf(Vs[rowv * VSTR + cb * 4 + (colb & 3)]);
      }
    }
    #pragma unroll
    for (int m = 0; m < 4; ++m)
      #pragma unroll
      for (int n = 0; n < 4; ++n)
        acc[m][n] = __builtin_amdgcn_mfma_f32_16x16x32_bf16(af[m], bfr[n], acc[m][n], 0, 0, 0);
    __syncthreads();
  }
  #pragma unroll
  for (int m = 0; m < 4; ++m){
    const int trow = t0 + wm + m * 16 + kg * 4;
    #pragma unroll
    for (int n = 0; n < 4; ++n){
      const int vcol = v0 + wn + n * 16 + cl;
      #pragma unroll
      for (int j = 0; j < 4; ++j)
        ctx[((size_t)b * TQn + trow + j) * DIM + vcol] = acc[m][n][j];
    }
  }
}

extern "C" void kernel_launch(void* const* d_in, const int* in_sizes, int n_in,
                              void* d_out, int out_size, void* d_ws, size_t ws_size,
                              hipStream_t stream){
  (void)in_sizes; (void)n_in; (void)out_size;
  const float* query  = (const float*)d_in[0];  // [1024][16][1024] == m-major [16384][1024]
  const float* keys   = (const float*)d_in[1];  // [16][1024][1024]
  const float* values = (const float*)d_in[2];  // [16][1024][1024]
  const float* mask   = (const float*)d_in[3];  // [16][1024]
  const float* Wm     = (const float*)d_in[4];  // [1024][1024]
  float* score = (float*)d_out;                              // [16][1024][1024]
  float* ctx   = score + (size_t)NB * TQn * DIM;             // qp-plane scratch then real ctx
  dim3 blk(256, 1, 1);
  dim3 blk512(512, 1, 1);

  const size_t M16 = (size_t)16 * 1024 * 1024;   // 16M shorts
  const size_t M1  = (size_t)1024 * 1024;
  const size_t need = (4 * M16 + M1) * 2;        // 130 MB
  if (ws_size >= need){
    short* w  = (short*)d_ws;
    short* qf = w;                 // query fp16 (single plane)
    short* kf = qf + M16;          // keys fp16 (single plane)
    short* wf = kf + M16;          // W fp16 (single plane)
    short* vT = wf + M1;           // values^T fp16 [b][v][s]
    short* sb = vT + M16;          // score fp16
    short* qph = (short*)ctx;      // qp fp16 single plane (m-major [16384][1024])

    k0_cvt16<<<dim3(16384, 1, 1), blk, 0, stream>>>(query, qf);
    k0_cvt16<<<dim3(16384, 1, 1), blk, 0, stream>>>(keys, kf);
    k0_cvt16<<<dim3(1024, 1, 1), blk, 0, stream>>>(Wm, wf);
    k0_vtrans<<<dim3(16, 16, 16), blk, 0, stream>>>(values, vT);
    // K1: qp = qf . wf^T  (fp16 1-chain) -> fp16 single plane
    gemm256<4, 3><<<dim3(4, 64, 1), blk512, 0, stream>>>(qf, nullptr, wf, nullptr,
        nullptr, qph, nullptr, 1, 0, 1, 0, 0);
    // K2: logits = qph . kf  (fp16 1-chain)
    gemm256<4, 0><<<dim3(4, 4, 16), blk512, 0, stream>>>(qph, nullptr, kf, nullptr,
        score, nullptr, nullptr, 16, 1, 1, 1024, 1024);
    k3_softmax<<<dim3(NB * TQn, 1, 1), blk, 0, stream>>>(score, mask, sb);
    // K4: ctx = sb . vT  (fp16 1-chain)
    gemm256<4, 0><<<dim3(4, 4, 16), blk512, 0, stream>>>(sb, nullptr, vT, nullptr,
        ctx, nullptr, nullptr, 1, 1024, 1, 1024, 1024);
  } else {
    k1_qp<<<dim3(DIM / BN, (TQn * NB) / BM, 1), blk, 0, stream>>>(query, Wm, ctx);
    k2_logits<<<dim3(DIM / BN, TQn / BM, NB), blk, 0, stream>>>(ctx, keys, score);
    k3_softmax<<<dim3(NB * TQn, 1, 1), blk, 0, stream>>>(score, mask, nullptr);
    k4_ctx<<<dim3(DIM / BN, TQn / BM, NB), blk, 0, stream>>>(score, values, ctx);
  }
}

// Round 15
// 227.616 us; speedup vs baseline: 1.1005x; 1.0516x over previous
//
#include <hip/hip_runtime.h>
#include <hip/hip_bf16.h>

#define TQn 1024
#define NB  16
#define DIM 1024
#define BM  128
#define BN  128
#define BK  32
#define STR 40
#define VSTR 132

typedef __attribute__((ext_vector_type(4))) float f32x4;
typedef __attribute__((ext_vector_type(8))) short s16x8;
typedef __attribute__((ext_vector_type(4))) short s16x4;
typedef __attribute__((ext_vector_type(8))) _Float16 h16x8;

__device__ __forceinline__ short f2bf(float f){
  union { float f; unsigned u; } v; v.f = f;
  unsigned r = v.u + 0x7fffu + ((v.u >> 16) & 1u);  // RNE
  return (short)(r >> 16);
}
__device__ __forceinline__ float bf2f(short h){
  union { unsigned u; float f; } v; v.u = ((unsigned)(unsigned short)h) << 16;
  return v.f;
}
__device__ __forceinline__ short f2h(float f){
  _Float16 h = (_Float16)f;
  return __builtin_bit_cast(short, h);
}

__device__ __forceinline__ void gload16(const short* g, short* l){
#if __has_builtin(__builtin_amdgcn_global_load_lds)
  __builtin_amdgcn_global_load_lds(
      (const __attribute__((address_space(1))) unsigned int*)(const void*)g,
      (__attribute__((address_space(3))) unsigned int*)(void*)l, 16, 0, 0);
#else
  *reinterpret_cast<s16x8*>(l) = *reinterpret_cast<const s16x8*>(g);
#endif
}

// CH=2 (fp16 2-chain) and CH=4 (fp16 1-chain) use fp16 MFMA; CH=1/3 bf16.
template<int CH>
__device__ __forceinline__ f32x4 mfma_frag(s16x8 a, s16x8 b, f32x4 c){
  if constexpr (CH == 2 || CH == 4)
    return __builtin_amdgcn_mfma_f32_16x16x32_f16(
        __builtin_bit_cast(h16x8, a), __builtin_bit_cast(h16x8, b), c, 0, 0, 0);
  else
    return __builtin_amdgcn_mfma_f32_16x16x32_bf16(a, b, c, 0, 0, 0);
}

// ---------------- fast path ----------------

// merged fp32 -> fp16 conversion for query(16M) + keys(16M) + W(1M)
__global__ __launch_bounds__(256) void k0_cvtall(const float* __restrict__ q,
                                                 const float* __restrict__ k,
                                                 const float* __restrict__ wm,
                                                 short* __restrict__ qf,
                                                 short* __restrict__ kf,
                                                 short* __restrict__ wf){
  const size_t NQ = (size_t)16 * 1024 * 1024;
  const size_t i = ((size_t)blockIdx.x * 256 + threadIdx.x) * 4;
  const float* in; short* out; size_t off;
  if (i < NQ){ in = q; out = qf; off = i; }
  else if (i < 2 * NQ){ in = k; out = kf; off = i - NQ; }
  else { in = wm; out = wf; off = i - 2 * NQ; }
  f32x4 v = *reinterpret_cast<const f32x4*>(in + off);
  s16x4 o;
  #pragma unroll
  for (int j = 0; j < 4; ++j) o[j] = f2h(v[j]);
  *reinterpret_cast<s16x4*>(out + off) = o;
}

// values [b][s][v] fp32 -> vT [b][v][s] fp16
__global__ __launch_bounds__(256) void k0_vtrans(const float* __restrict__ vals,
                                                 short* __restrict__ vT){
  __shared__ short T[64 * 72];
  const int t = threadIdx.x;
  const int v0 = blockIdx.x * 64, s0 = blockIdx.y * 64, b = blockIdx.z;
  const int r16 = t >> 4, c4 = (t & 15) * 4;
  #pragma unroll
  for (int i = 0; i < 4; ++i){
    const int sl = i * 16 + r16;
    f32x4 v = *reinterpret_cast<const f32x4*>(vals + ((size_t)b * TQn + s0 + sl) * DIM + v0 + c4);
    #pragma unroll
    for (int j = 0; j < 4; ++j) T[(c4 + j) * 72 + sl] = f2h(v[j]);
  }
  __syncthreads();
  #pragma unroll
  for (int i = 0; i < 4; ++i){
    const int vl = i * 16 + r16;
    s16x4 o = *reinterpret_cast<const s16x4*>(&T[vl * 72 + c4]);
    *reinterpret_cast<s16x4*>(vT + ((size_t)b * DIM + v0 + vl) * TQn + s0 + c4) = o;
  }
}

// 256x256 A*B^T GEMM, 8 waves (2Mx4N), BK=64, dbuf 128KB, fragment-major
// (conflict-free b128), r12 counted-vmcnt 4-phase pipeline (best config),
// plus XCD-chunked block swizzle (T1):
//  SWZ=1 (grid 4,4,16): all 16 blocks of one bz land on one XCD -> that
//        bz's 8 A/B panels (4MB) fit the XCD's 4MB L2; re-reads become L2 hits.
//  SWZ=2 (grid 4,64,1): the 4 bx-blocks sharing an A-panel land together.
// Pure work permutation: results bit-identical.
// CH=3: bf16 3x1024 ; CH=2: fp16 2x1024 ; CH=1: bf16 ; CH=4: fp16 plain
// EPI: 0 = fp32 C; 1 = bf16 hi/lo; 2 = fp16 hi/lo; 3 = fp16 single plane
template<int CH, int EPI, int SWZ>
__global__ __launch_bounds__(512, 2) void gemm256(
    const short* __restrict__ Ah, const short* __restrict__ Al,
    const short* __restrict__ Bh, const short* __restrict__ Bl,
    float* __restrict__ C, short* __restrict__ Ch, short* __restrict__ Cl,
    int ARS, int ABO, int BRS, int BBO, int CBO)
{
  constexpr int NSTEP = (CH == 3) ? 48 : (CH == 2) ? 32 : 16;
  __shared__ __align__(16) short lds[2 * 32768];   // 128 KB
  const int tid = threadIdx.x;
  const int lane = tid & 63, w = tid >> 6;
  const int cl = lane & 15, kg = lane >> 4;
  const int lane8 = lane * 8;
  int bx, by, bz;
  if (SWZ == 1){
    const int lin = blockIdx.x + 4 * (blockIdx.y + 4 * blockIdx.z);  // 0..255
    const int xcd = lin & 7, idx = lin >> 3;                          // idx 0..31
    bz = 2 * xcd + (idx >> 4);
    const int rem = idx & 15;
    by = rem >> 2; bx = rem & 3;
  } else if (SWZ == 2){
    const int lin = blockIdx.x + 4 * blockIdx.y;                      // 0..255
    const int xcd = lin & 7, idx = lin >> 3;                          // idx 0..31
    by = xcd * 8 + (idx >> 2); bx = idx & 3; bz = 0;
  } else {
    bx = blockIdx.x; by = blockIdx.y; bz = blockIdx.z;
  }
  const int wr = w >> 2, wc = w & 3;

  int aoffE[2], boffE[2], aldsE[2], bldsE[2];
  #pragma unroll
  for (int l = 0; l < 2; ++l){
    const int rg = 2 * w + l;
    const int arow = by * 256 + rg * 16 + cl;
    const int brow = bx * 256 + rg * 16 + cl;
    aoffE[l] = (arow * ARS + bz * ABO) * 1024 + kg * 8;
    boffE[l] = (brow * BRS + bz * BBO) * 1024 + kg * 8;
    aldsE[l] = (4 * w + 2 * l) * 512 + lane8;
    bldsE[l] = 16384 + (4 * w + 2 * l) * 512 + lane8;
  }

  f32x4 acc[8][4] = {};

  // prologue: stage tile 0 (chain 0 -> Ah,Bh) in deadline order; kk1 stays in flight.
  #pragma unroll
  for (int l = 0; l < 2; ++l) gload16(Bh + (size_t)boffE[l], &lds[bldsE[l]]);
  #pragma unroll
  for (int l = 0; l < 2; ++l) gload16(Ah + (size_t)aoffE[l], &lds[aldsE[l]]);
  #pragma unroll
  for (int l = 0; l < 2; ++l) gload16(Bh + (size_t)(boffE[l] + 32), &lds[bldsE[l] + 512]);
  #pragma unroll
  for (int l = 0; l < 2; ++l) gload16(Ah + (size_t)(aoffE[l] + 32), &lds[aldsE[l] + 512]);
  asm volatile("s_waitcnt vmcnt(4)" ::: "memory");
  __builtin_amdgcn_s_barrier();
  __builtin_amdgcn_sched_barrier(0);

  for (int t = 0; t < NSTEP; ++t){
    const int buf = (t & 1) * 32768;
    const int nbuf = buf ^ 32768;
    const bool pf = (t + 1 < NSTEP);
    int k1 = 0; const short *PA = Ah, *PB = Bh;
    if (pf){
      if (CH == 3){
        const int cc = (t + 1) % 3;
        k1 = ((t + 1) / 3) * 64;
        PA = (cc == 1) ? Al : Ah;
        PB = (cc == 2) ? Bl : Bh;
      } else if (CH == 2){
        k1 = ((t + 1) >> 1) * 64;
        PA = ((t + 1) & 1) ? Al : Ah;
        PB = Bh;
      } else k1 = (t + 1) * 64;
    }

    s16x8 av[4], bv[4];
    // ---- ph0: quad (m0-3, kk0); issue t+1 B-kk0 ----
    #pragma unroll
    for (int m = 0; m < 4; ++m)
      av[m] = *reinterpret_cast<const s16x8*>(&lds[buf + ((wr * 8 + m) * 2 + 0) * 512 + lane8]);
    #pragma unroll
    for (int n = 0; n < 4; ++n)
      bv[n] = *reinterpret_cast<const s16x8*>(&lds[buf + 16384 + ((wc * 4 + n) * 2 + 0) * 512 + lane8]);
    if (pf){
      #pragma unroll
      for (int l = 0; l < 2; ++l) gload16(PB + (size_t)(boffE[l] + k1), &lds[nbuf + bldsE[l]]);
    }
    __builtin_amdgcn_s_barrier();
    __builtin_amdgcn_s_setprio(1);
    #pragma unroll
    for (int m = 0; m < 4; ++m)
      #pragma unroll
      for (int n = 0; n < 4; ++n)
        acc[m][n] = mfma_frag<CH>(av[m], bv[n], acc[m][n]);
    __builtin_amdgcn_s_setprio(0);
    __builtin_amdgcn_s_barrier();
    // ---- ph1: quad (m4-7, kk0), bv reused; issue t+1 A-kk0 ----
    #pragma unroll
    for (int m = 0; m < 4; ++m)
      av[m] = *reinterpret_cast<const s16x8*>(&lds[buf + ((wr * 8 + 4 + m) * 2 + 0) * 512 + lane8]);
    if (pf){
      #pragma unroll
      for (int l = 0; l < 2; ++l) gload16(PA + (size_t)(aoffE[l] + k1), &lds[nbuf + aldsE[l]]);
    }
    __builtin_amdgcn_s_barrier();
    __builtin_amdgcn_s_setprio(1);
    #pragma unroll
    for (int m = 0; m < 4; ++m)
      #pragma unroll
      for (int n = 0; n < 4; ++n)
        acc[4 + m][n] = mfma_frag<CH>(av[m], bv[n], acc[4 + m][n]);
    __builtin_amdgcn_s_setprio(0);
    if (pf) asm volatile("s_waitcnt vmcnt(4)" ::: "memory");
    else    asm volatile("s_waitcnt vmcnt(0)" ::: "memory");
    __builtin_amdgcn_s_barrier();
    __builtin_amdgcn_sched_barrier(0);
    // ---- ph2: quad (m0-3, kk1); issue t+1 B-kk1 ----
    #pragma unroll
    for (int m = 0; m < 4; ++m)
      av[m] = *reinterpret_cast<const s16x8*>(&lds[buf + ((wr * 8 + m) * 2 + 1) * 512 + lane8]);
    #pragma unroll
    for (int n = 0; n < 4; ++n)
      bv[n] = *reinterpret_cast<const s16x8*>(&lds[buf + 16384 + ((wc * 4 + n) * 2 + 1) * 512 + lane8]);
    if (pf){
      #pragma unroll
      for (int l = 0; l < 2; ++l) gload16(PB + (size_t)(boffE[l] + k1 + 32), &lds[nbuf + bldsE[l] + 512]);
    }
    __builtin_amdgcn_s_barrier();
    __builtin_amdgcn_s_setprio(1);
    #pragma unroll
    for (int m = 0; m < 4; ++m)
      #pragma unroll
      for (int n = 0; n < 4; ++n)
        acc[m][n] = mfma_frag<CH>(av[m], bv[n], acc[m][n]);
    __builtin_amdgcn_s_setprio(0);
    __builtin_amdgcn_s_barrier();
    // ---- ph3: quad (m4-7, kk1), bv reused; issue t+1 A-kk1 ----
    #pragma unroll
    for (int m = 0; m < 4; ++m)
      av[m] = *reinterpret_cast<const s16x8*>(&lds[buf + ((wr * 8 + 4 + m) * 2 + 1) * 512 + lane8]);
    if (pf){
      #pragma unroll
      for (int l = 0; l < 2; ++l) gload16(PA + (size_t)(aoffE[l] + k1 + 32), &lds[nbuf + aldsE[l] + 512]);
    }
    __builtin_amdgcn_s_barrier();
    __builtin_amdgcn_s_setprio(1);
    #pragma unroll
    for (int m = 0; m < 4; ++m)
      #pragma unroll
      for (int n = 0; n < 4; ++n)
        acc[4 + m][n] = mfma_frag<CH>(av[m], bv[n], acc[4 + m][n]);
    __builtin_amdgcn_s_setprio(0);
    if (pf){
      asm volatile("s_waitcnt vmcnt(4)" ::: "memory");
      __builtin_amdgcn_s_barrier();
      __builtin_amdgcn_sched_barrier(0);
    }
  }

  #pragma unroll
  for (int m = 0; m < 8; ++m){
    const int row0 = by * 256 + wr * 128 + m * 16 + kg * 4;
    #pragma unroll
    for (int n = 0; n < 4; ++n){
      const int col = bx * 256 + wc * 64 + n * 16 + cl;
      #pragma unroll
      for (int j = 0; j < 4; ++j){
        const size_t off = ((size_t)(row0 + j) + (size_t)bz * CBO) * 1024 + col;
        if (EPI == 0) C[off] = acc[m][n][j];
        else if (EPI == 1){
          const float v = acc[m][n][j];
          const short hh = f2bf(v);
          Ch[off] = hh; Cl[off] = f2bf(v - bf2f(hh));
        } else if (EPI == 2){
          const float v = acc[m][n][j];
          const _Float16 hh = (_Float16)v;
          Ch[off] = __builtin_bit_cast(short, hh);
          const _Float16 ll = (_Float16)(v - (float)hh);
          Cl[off] = __builtin_bit_cast(short, ll);
        } else {
          Ch[off] = f2h(acc[m][n][j]);
        }
      }
    }
  }
}

// K3: in-place row softmax of (logits + mask[b][s]); optional fp16 copy for K4
__global__ __launch_bounds__(256) void k3_softmax(float* __restrict__ logits,
                                                  const float* __restrict__ mask,
                                                  short* __restrict__ sbf){
  const int row = blockIdx.x;       // b*TQ + t
  const int b = row >> 10;
  const int tid = threadIdx.x;
  float* p = logits + (size_t)row * DIM;
  f32x4 v  = *reinterpret_cast<const f32x4*>(p + tid * 4);
  f32x4 mk = *reinterpret_cast<const f32x4*>(mask + (size_t)b * DIM + tid * 4);
  v = v + mk;
  float mx = fmaxf(fmaxf(v[0], v[1]), fmaxf(v[2], v[3]));
  #pragma unroll
  for (int off = 32; off; off >>= 1) mx = fmaxf(mx, __shfl_xor(mx, off));
  __shared__ float red[8];
  const int lane = tid & 63, wid = tid >> 6;
  if (lane == 0) red[wid] = mx;
  __syncthreads();
  mx = fmaxf(fmaxf(red[0], red[1]), fmaxf(red[2], red[3]));
  f32x4 e;
  #pragma unroll
  for (int j = 0; j < 4; ++j) e[j] = __expf(v[j] - mx);
  float s = e[0] + e[1] + e[2] + e[3];
  #pragma unroll
  for (int off = 32; off; off >>= 1) s += __shfl_xor(s, off);
  if (lane == 0) red[4 + wid] = s;
  __syncthreads();
  s = red[4] + red[5] + red[6] + red[7];
  const float inv = 1.0f / s;
  f32x4 o;
  s16x4 ob;
  #pragma unroll
  for (int j = 0; j < 4; ++j){ o[j] = e[j] * inv; ob[j] = f2h(o[j]); }
  *reinterpret_cast<f32x4*>(p + tid * 4) = o;
  if (sbf) *reinterpret_cast<s16x4*>(sbf + (size_t)row * DIM + tid * 4) = ob;
}

// ---------------- fallback (round-3 passing) kernels ----------------

__global__ __launch_bounds__(256) void k1_qp(const float* __restrict__ A,
                                             const float* __restrict__ Wm,
                                             float* __restrict__ C){
  __shared__ __align__(16) short Ah[BM * STR];
  __shared__ __align__(16) short Al[BM * STR];
  __shared__ __align__(16) short Bh[BN * STR];
  __shared__ __align__(16) short Bl[BN * STR];
  const int tid = threadIdx.x;
  const int m0 = blockIdx.y * BM, n0 = blockIdx.x * BN;
  const int lane = tid & 63, wid = tid >> 6;
  const int wm = (wid >> 1) * 64, wn = (wid & 1) * 64;
  const int cl = lane & 15, kg = lane >> 4;
  const int rr = tid >> 3, f4 = (tid & 7) * 4;
  f32x4 acc[4][4] = {};
  for (int k0 = 0; k0 < DIM; k0 += BK){
    #pragma unroll
    for (int i = 0; i < 4; ++i){
      const int r = rr + i * 32;
      f32x4 va = *reinterpret_cast<const f32x4*>(A  + (size_t)(m0 + r) * DIM + k0 + f4);
      f32x4 vb = *reinterpret_cast<const f32x4*>(Wm + (size_t)(n0 + r) * DIM + k0 + f4);
      s16x4 ha, la, hb, lb;
      #pragma unroll
      for (int j = 0; j < 4; ++j){
        ha[j] = f2bf(va[j]); la[j] = f2bf(va[j] - bf2f(ha[j]));
        hb[j] = f2bf(vb[j]); lb[j] = f2bf(vb[j] - bf2f(hb[j]));
      }
      *reinterpret_cast<s16x4*>(&Ah[r * STR + f4]) = ha;
      *reinterpret_cast<s16x4*>(&Al[r * STR + f4]) = la;
      *reinterpret_cast<s16x4*>(&Bh[r * STR + f4]) = hb;
      *reinterpret_cast<s16x4*>(&Bl[r * STR + f4]) = lb;
    }
    __syncthreads();
    s16x8 ah[4], al8[4], bh8[4], bl8[4];
    #pragma unroll
    for (int m = 0; m < 4; ++m){
      ah[m]  = *reinterpret_cast<const s16x8*>(&Ah[(wm + m * 16 + cl) * STR + kg * 8]);
      al8[m] = *reinterpret_cast<const s16x8*>(&Al[(wm + m * 16 + cl) * STR + kg * 8]);
    }
    #pragma unroll
    for (int n = 0; n < 4; ++n){
      bh8[n] = *reinterpret_cast<const s16x8*>(&Bh[(wn + n * 16 + cl) * STR + kg * 8]);
      bl8[n] = *reinterpret_cast<const s16x8*>(&Bl[(wn + n * 16 + cl) * STR + kg * 8]);
    }
    #pragma unroll
    for (int m = 0; m < 4; ++m)
      #pragma unroll
      for (int n = 0; n < 4; ++n){
        acc[m][n] = __builtin_amdgcn_mfma_f32_16x16x32_bf16(ah[m],  bh8[n], acc[m][n], 0, 0, 0);
        acc[m][n] = __builtin_amdgcn_mfma_f32_16x16x32_bf16(al8[m], bh8[n], acc[m][n], 0, 0, 0);
        acc[m][n] = __builtin_amdgcn_mfma_f32_16x16x32_bf16(ah[m],  bl8[n], acc[m][n], 0, 0, 0);
      }
    __syncthreads();
  }
  #pragma unroll
  for (int m = 0; m < 4; ++m){
    const int row = m0 + wm + m * 16 + kg * 4;
    #pragma unroll
    for (int n = 0; n < 4; ++n){
      const int col = n0 + wn + n * 16 + cl;
      #pragma unroll
      for (int j = 0; j < 4; ++j)
        C[(size_t)(row + j) * DIM + col] = acc[m][n][j];
    }
  }
}

__global__ __launch_bounds__(256) void k2_logits(const float* __restrict__ qp,
                                                 const float* __restrict__ keys,
                                                 float* __restrict__ out){
  __shared__ __align__(16) short Ah[BM * STR];
  __shared__ __align__(16) short Al[BM * STR];
  __shared__ __align__(16) short Bh[BN * STR];
  __shared__ __align__(16) short Bl[BN * STR];
  const int tid = threadIdx.x;
  const int b = blockIdx.z;
  const int t0 = blockIdx.y * BM, s0 = blockIdx.x * BN;
  const int lane = tid & 63, wid = tid >> 6;
  const int wm = (wid >> 1) * 64, wn = (wid & 1) * 64;
  const int cl = lane & 15, kg = lane >> 4;
  const int rr = tid >> 3, f4 = (tid & 7) * 4;
  f32x4 acc[4][4] = {};
  for (int k0 = 0; k0 < DIM; k0 += BK){
    #pragma unroll
    for (int i = 0; i < 4; ++i){
      const int r = rr + i * 32;
      f32x4 va = *reinterpret_cast<const f32x4*>(qp   + (size_t)((t0 + r) * NB + b) * DIM + k0 + f4);
      f32x4 vb = *reinterpret_cast<const f32x4*>(keys + ((size_t)b * DIM + s0 + r) * DIM + k0 + f4);
      s16x4 ha, la, hb, lb;
      #pragma unroll
      for (int j = 0; j < 4; ++j){
        ha[j] = f2bf(va[j]); la[j] = f2bf(va[j] - bf2f(ha[j]));
        hb[j] = f2bf(vb[j]); lb[j] = f2bf(vb[j] - bf2f(hb[j]));
      }
      *reinterpret_cast<s16x4*>(&Ah[r * STR + f4]) = ha;
      *reinterpret_cast<s16x4*>(&Al[r * STR + f4]) = la;
      *reinterpret_cast<s16x4*>(&Bh[r * STR + f4]) = hb;
      *reinterpret_cast<s16x4*>(&Bl[r * STR + f4]) = lb;
    }
    __syncthreads();
    s16x8 ah[4], al8[4], bh8[4], bl8[4];
    #pragma unroll
    for (int m = 0; m < 4; ++m){
      ah[m]  = *reinterpret_cast<const s16x8*>(&Ah[(wm + m * 16 + cl) * STR + kg * 8]);
      al8[m] = *reinterpret_cast<const s16x8*>(&Al[(wm + m * 16 + cl) * STR + kg * 8]);
    }
    #pragma unroll
    for (int n = 0; n < 4; ++n){
      bh8[n] = *reinterpret_cast<const s16x8*>(&Bh[(wn + n * 16 + cl) * STR + kg * 8]);
      bl8[n] = *reinterpret_cast<const s16x8*>(&Bl[(wn + n * 16 + cl) * STR + kg * 8]);
    }
    #pragma unroll
    for (int m = 0; m < 4; ++m)
      #pragma unroll
      for (int n = 0; n < 4; ++n){
        acc[m][n] = __builtin_amdgcn_mfma_f32_16x16x32_bf16(ah[m],  bh8[n], acc[m][n], 0, 0, 0);
        acc[m][n] = __builtin_amdgcn_mfma_f32_16x16x32_bf16(al8[m], bh8[n], acc[m][n], 0, 0, 0);
        acc[m][n] = __builtin_amdgcn_mfma_f32_16x16x32_bf16(ah[m],  bl8[n], acc[m][n], 0, 0, 0);
      }
    __syncthreads();
  }
  #pragma unroll
  for (int m = 0; m < 4; ++m){
    const int trow = t0 + wm + m * 16 + kg * 4;
    #pragma unroll
    for (int n = 0; n < 4; ++n){
      const int scol = s0 + wn + n * 16 + cl;
      #pragma unroll
      for (int j = 0; j < 4; ++j)
        out[((size_t)b * TQn + trow + j) * DIM + scol] = acc[m][n][j];
    }
  }
}

__global__ __launch_bounds__(256) void k4_ctx(const float* __restrict__ score,
                                              const float* __restrict__ values,
                                              float* __restrict__ ctx){
  __shared__ __align__(16) short As[BM * STR];
  __shared__ __align__(16) float Vs[BK * VSTR];
  const int tid = threadIdx.x;
  const int b = blockIdx.z;
  const int t0 = blockIdx.y * BM, v0 = blockIdx.x * BN;
  const int lane = tid & 63, wid = tid >> 6;
  const int wm = (wid >> 1) * 64, wn = (wid & 1) * 64;
  const int cl = lane & 15, kg = lane >> 4;
  const int rr = tid >> 3, f4 = (tid & 7) * 4;
  const int vr = tid >> 5, vc = tid & 31;
  f32x4 acc[4][4] = {};
  for (int k0 = 0; k0 < DIM; k0 += BK){
    #pragma unroll
    for (int i = 0; i < 4; ++i){
      const int r = rr + i * 32;
      f32x4 va = *reinterpret_cast<const f32x4*>(score + ((size_t)b * TQn + t0 + r) * DIM + k0 + f4);
      s16x4 ha;
      #pragma unroll
      for (int j = 0; j < 4; ++j) ha[j] = f2bf(va[j]);
      *reinterpret_cast<s16x4*>(&As[r * STR + f4]) = ha;
      const int vrow = vr + i * 8;
      f32x4 vv = *reinterpret_cast<const f32x4*>(values + ((size_t)b * DIM + k0 + vrow) * DIM + v0 + vc * 4);
      const int cb = vc ^ (((vrow >> 3) & 1) << 2);
      *reinterpret_cast<f32x4*>(&Vs[vrow * VSTR + cb * 4]) = vv;
    }
    __syncthreads();
    s16x8 af[4], bfr[4];
    #pragma unroll
    for (int m = 0; m < 4; ++m)
      af[m] = *reinterpret_cast<const s16x8*>(&As[(wm + m * 16 + cl) * STR + kg * 8]);
    #pragma unroll
    for (int n = 0; n < 4; ++n){
      const int colb = wn + n * 16 + cl;
      const int cb = (colb >> 2) ^ ((kg & 1) << 2);
      #pragma unroll
      for (int j = 0; j < 8; ++j){
        const int rowv = kg * 8 + j;
        bfr[n][j] = f2bf(Vs[rowv * VSTR + cb * 4 + (colb & 3)]);
      }
    }
    #pragma unroll
    for (int m = 0; m < 4; ++m)
      #pragma unroll
      for (int n = 0; n < 4; ++n)
        acc[m][n] = __builtin_amdgcn_mfma_f32_16x16x32_bf16(af[m], bfr[n], acc[m][n], 0, 0, 0);
    __syncthreads();
  }
  #pragma unroll
  for (int m = 0; m < 4; ++m){
    const int trow = t0 + wm + m * 16 + kg * 4;
    #pragma unroll
    for (int n = 0; n < 4; ++n){
      const int vcol = v0 + wn + n * 16 + cl;
      #pragma unroll
      for (int j = 0; j < 4; ++j)
        ctx[((size_t)b * TQn + trow + j) * DIM + vcol] = acc[m][n][j];
    }
  }
}

extern "C" void kernel_launch(void* const* d_in, const int* in_sizes, int n_in,
                              void* d_out, int out_size, void* d_ws, size_t ws_size,
                              hipStream_t stream){
  (void)in_sizes; (void)n_in; (void)out_size;
  const float* query  = (const float*)d_in[0];  // [1024][16][1024] == m-major [16384][1024]
  const float* keys   = (const float*)d_in[1];  // [16][1024][1024]
  const float* values = (const float*)d_in[2];  // [16][1024][1024]
  const float* mask   = (const float*)d_in[3];  // [16][1024]
  const float* Wm     = (const float*)d_in[4];  // [1024][1024]
  float* score = (float*)d_out;                              // [16][1024][1024]
  float* ctx   = score + (size_t)NB * TQn * DIM;             // qp-plane scratch then real ctx
  dim3 blk(256, 1, 1);
  dim3 blk512(512, 1, 1);

  const size_t M16 = (size_t)16 * 1024 * 1024;   // 16M shorts
  const size_t M1  = (size_t)1024 * 1024;
  const size_t need = (4 * M16 + M1) * 2;        // 130 MB
  if (ws_size >= need){
    short* w  = (short*)d_ws;
    short* qf = w;                 // query fp16 (single plane)
    short* kf = qf + M16;          // keys fp16 (single plane)
    short* wf = kf + M16;          // W fp16 (single plane)
    short* vT = wf + M1;           // values^T fp16 [b][v][s]
    short* sb = vT + M16;          // score fp16
    short* qph = (short*)ctx;      // qp fp16 single plane (m-major [16384][1024])

    k0_cvtall<<<dim3(33792, 1, 1), blk, 0, stream>>>(query, keys, Wm, qf, kf, wf);
    k0_vtrans<<<dim3(16, 16, 16), blk, 0, stream>>>(values, vT);
    // K1: qp = qf . wf^T  (fp16 1-chain) -> fp16 single plane, A-panel-grouped swizzle
    gemm256<4, 3, 2><<<dim3(4, 64, 1), blk512, 0, stream>>>(qf, nullptr, wf, nullptr,
        nullptr, qph, nullptr, 1, 0, 1, 0, 0);
    // K2: logits = qph . kf  (fp16 1-chain), bz-per-XCD swizzle
    gemm256<4, 0, 1><<<dim3(4, 4, 16), blk512, 0, stream>>>(qph, nullptr, kf, nullptr,
        score, nullptr, nullptr, 16, 1, 1, 1024, 1024);
    k3_softmax<<<dim3(NB * TQn, 1, 1), blk, 0, stream>>>(score, mask, sb);
    // K4: ctx = sb . vT  (fp16 1-chain), bz-per-XCD swizzle
    gemm256<4, 0, 1><<<dim3(4, 4, 16), blk512, 0, stream>>>(sb, nullptr, vT, nullptr,
        ctx, nullptr, nullptr, 1, 1024, 1, 1024, 1024);
  } else {
    k1_qp<<<dim3(DIM / BN, (TQn * NB) / BM, 1), blk, 0, stream>>>(query, Wm, ctx);
    k2_logits<<<dim3(DIM / BN, TQn / BM, NB), blk, 0, stream>>>(ctx, keys, score);
    k3_softmax<<<dim3(NB * TQn, 1, 1), blk, 0, stream>>>(score, mask, nullptr);
    k4_ctx<<<dim3(DIM / BN, TQn / BM, NB), blk, 0, stream>>>(score, values, ctx);
  }
}

// Round 16
// 225.899 us; speedup vs baseline: 1.1088x; 1.0076x over previous
//
#include <hip/hip_runtime.h>
#include <hip/hip_bf16.h>

#define TQn 1024
#define NB  16
#define DIM 1024
#define BM  128
#define BN  128
#define BK  32
#define STR 40
#define VSTR 132

typedef __attribute__((ext_vector_type(4))) float f32x4;
typedef __attribute__((ext_vector_type(8))) short s16x8;
typedef __attribute__((ext_vector_type(4))) short s16x4;
typedef __attribute__((ext_vector_type(8))) _Float16 h16x8;

__device__ __forceinline__ short f2bf(float f){
  union { float f; unsigned u; } v; v.f = f;
  unsigned r = v.u + 0x7fffu + ((v.u >> 16) & 1u);  // RNE
  return (short)(r >> 16);
}
__device__ __forceinline__ float bf2f(short h){
  union { unsigned u; float f; } v; v.u = ((unsigned)(unsigned short)h) << 16;
  return v.f;
}
__device__ __forceinline__ short f2h(float f){
  _Float16 h = (_Float16)f;
  return __builtin_bit_cast(short, h);
}

__device__ __forceinline__ void gload16(const short* g, short* l){
#if __has_builtin(__builtin_amdgcn_global_load_lds)
  __builtin_amdgcn_global_load_lds(
      (const __attribute__((address_space(1))) unsigned int*)(const void*)g,
      (__attribute__((address_space(3))) unsigned int*)(void*)l, 16, 0, 0);
#else
  *reinterpret_cast<s16x8*>(l) = *reinterpret_cast<const s16x8*>(g);
#endif
}

// CH=2 (fp16 2-chain) and CH=4 (fp16 1-chain) use fp16 MFMA; CH=1/3 bf16.
template<int CH>
__device__ __forceinline__ f32x4 mfma_frag(s16x8 a, s16x8 b, f32x4 c){
  if constexpr (CH == 2 || CH == 4)
    return __builtin_amdgcn_mfma_f32_16x16x32_f16(
        __builtin_bit_cast(h16x8, a), __builtin_bit_cast(h16x8, b), c, 0, 0, 0);
  else
    return __builtin_amdgcn_mfma_f32_16x16x32_bf16(a, b, c, 0, 0, 0);
}

// ---------------- fast path ----------------

// merged k0: blocks [0,33792) convert query/keys/W fp32->fp16 planes;
// blocks [33792,37888) transpose values [b][s][v] fp32 -> vT [b][v][s] fp16.
__global__ __launch_bounds__(256) void k0_all(const float* __restrict__ q,
                                              const float* __restrict__ k,
                                              const float* __restrict__ wm,
                                              const float* __restrict__ vals,
                                              short* __restrict__ qf,
                                              short* __restrict__ kf,
                                              short* __restrict__ wf,
                                              short* __restrict__ vT){
  __shared__ short T[64 * 72];
  const int bid = blockIdx.x;
  if (bid < 33792){
    const size_t NQ = (size_t)16 * 1024 * 1024;
    const size_t i = ((size_t)bid * 256 + threadIdx.x) * 4;
    const float* in; short* out; size_t off;
    if (i < NQ){ in = q; out = qf; off = i; }
    else if (i < 2 * NQ){ in = k; out = kf; off = i - NQ; }
    else { in = wm; out = wf; off = i - 2 * NQ; }
    f32x4 v = *reinterpret_cast<const f32x4*>(in + off);
    s16x4 o;
    #pragma unroll
    for (int j = 0; j < 4; ++j) o[j] = f2h(v[j]);
    *reinterpret_cast<s16x4*>(out + off) = o;
  } else {
    const int idx = bid - 33792;                 // 0..4095
    const int v0 = (idx & 15) * 64;
    const int s0 = ((idx >> 4) & 15) * 64;
    const int b  = idx >> 8;
    const int t = threadIdx.x;
    const int r16 = t >> 4, c4 = (t & 15) * 4;
    #pragma unroll
    for (int i = 0; i < 4; ++i){
      const int sl = i * 16 + r16;
      f32x4 v = *reinterpret_cast<const f32x4*>(vals + ((size_t)b * TQn + s0 + sl) * DIM + v0 + c4);
      #pragma unroll
      for (int j = 0; j < 4; ++j) T[(c4 + j) * 72 + sl] = f2h(v[j]);
    }
    __syncthreads();
    #pragma unroll
    for (int i = 0; i < 4; ++i){
      const int vl = i * 16 + r16;
      s16x4 o = *reinterpret_cast<const s16x4*>(&T[vl * 72 + c4]);
      *reinterpret_cast<s16x4*>(vT + ((size_t)b * DIM + v0 + vl) * TQn + s0 + c4) = o;
    }
  }
}

// 256x256 A*B^T GEMM, 8 waves (2Mx4N), BK=64, dbuf 128KB, fragment-major
// (conflict-free b128), r12 counted-vmcnt 4-phase pipeline + XCD swizzle (T1).
//  SWZ=1 (grid 4,4,16): all 16 blocks of one bz on one XCD (panels fit its L2).
//  SWZ=2 (grid 4,64,1): the 4 bx-blocks sharing an A-panel land together.
// CH=4: fp16 plain 1024 (the only chain config used in the fast path now).
// EPI: 0 = fp32 C; 3 = fp16 single plane.
template<int CH, int EPI, int SWZ>
__global__ __launch_bounds__(512, 2) void gemm256(
    const short* __restrict__ Ah, const short* __restrict__ Al,
    const short* __restrict__ Bh, const short* __restrict__ Bl,
    float* __restrict__ C, short* __restrict__ Ch, short* __restrict__ Cl,
    int ARS, int ABO, int BRS, int BBO, int CBO)
{
  constexpr int NSTEP = (CH == 3) ? 48 : (CH == 2) ? 32 : 16;
  __shared__ __align__(16) short lds[2 * 32768];   // 128 KB
  const int tid = threadIdx.x;
  const int lane = tid & 63, w = tid >> 6;
  const int cl = lane & 15, kg = lane >> 4;
  const int lane8 = lane * 8;
  int bx, by, bz;
  if (SWZ == 1){
    const int lin = blockIdx.x + 4 * (blockIdx.y + 4 * blockIdx.z);  // 0..255
    const int xcd = lin & 7, idx = lin >> 3;                          // idx 0..31
    bz = 2 * xcd + (idx >> 4);
    const int rem = idx & 15;
    by = rem >> 2; bx = rem & 3;
  } else if (SWZ == 2){
    const int lin = blockIdx.x + 4 * blockIdx.y;                      // 0..255
    const int xcd = lin & 7, idx = lin >> 3;                          // idx 0..31
    by = xcd * 8 + (idx >> 2); bx = idx & 3; bz = 0;
  } else {
    bx = blockIdx.x; by = blockIdx.y; bz = blockIdx.z;
  }
  const int wr = w >> 2, wc = w & 3;

  int aoffE[2], boffE[2], aldsE[2], bldsE[2];
  #pragma unroll
  for (int l = 0; l < 2; ++l){
    const int rg = 2 * w + l;
    const int arow = by * 256 + rg * 16 + cl;
    const int brow = bx * 256 + rg * 16 + cl;
    aoffE[l] = (arow * ARS + bz * ABO) * 1024 + kg * 8;
    boffE[l] = (brow * BRS + bz * BBO) * 1024 + kg * 8;
    aldsE[l] = (4 * w + 2 * l) * 512 + lane8;
    bldsE[l] = 16384 + (4 * w + 2 * l) * 512 + lane8;
  }

  f32x4 acc[8][4] = {};

  // prologue: stage tile 0 in deadline order; kk1 stays in flight.
  #pragma unroll
  for (int l = 0; l < 2; ++l) gload16(Bh + (size_t)boffE[l], &lds[bldsE[l]]);
  #pragma unroll
  for (int l = 0; l < 2; ++l) gload16(Ah + (size_t)aoffE[l], &lds[aldsE[l]]);
  #pragma unroll
  for (int l = 0; l < 2; ++l) gload16(Bh + (size_t)(boffE[l] + 32), &lds[bldsE[l] + 512]);
  #pragma unroll
  for (int l = 0; l < 2; ++l) gload16(Ah + (size_t)(aoffE[l] + 32), &lds[aldsE[l] + 512]);
  asm volatile("s_waitcnt vmcnt(4)" ::: "memory");
  __builtin_amdgcn_s_barrier();
  __builtin_amdgcn_sched_barrier(0);

  for (int t = 0; t < NSTEP; ++t){
    const int buf = (t & 1) * 32768;
    const int nbuf = buf ^ 32768;
    const bool pf = (t + 1 < NSTEP);
    int k1 = 0; const short *PA = Ah, *PB = Bh;
    if (pf){
      if (CH == 3){
        const int cc = (t + 1) % 3;
        k1 = ((t + 1) / 3) * 64;
        PA = (cc == 1) ? Al : Ah;
        PB = (cc == 2) ? Bl : Bh;
      } else if (CH == 2){
        k1 = ((t + 1) >> 1) * 64;
        PA = ((t + 1) & 1) ? Al : Ah;
        PB = Bh;
      } else k1 = (t + 1) * 64;
    }

    s16x8 av[4], bv[4];
    // ---- ph0: quad (m0-3, kk0); issue t+1 B-kk0 ----
    #pragma unroll
    for (int m = 0; m < 4; ++m)
      av[m] = *reinterpret_cast<const s16x8*>(&lds[buf + ((wr * 8 + m) * 2 + 0) * 512 + lane8]);
    #pragma unroll
    for (int n = 0; n < 4; ++n)
      bv[n] = *reinterpret_cast<const s16x8*>(&lds[buf + 16384 + ((wc * 4 + n) * 2 + 0) * 512 + lane8]);
    if (pf){
      #pragma unroll
      for (int l = 0; l < 2; ++l) gload16(PB + (size_t)(boffE[l] + k1), &lds[nbuf + bldsE[l]]);
    }
    __builtin_amdgcn_s_barrier();
    __builtin_amdgcn_s_setprio(1);
    #pragma unroll
    for (int m = 0; m < 4; ++m)
      #pragma unroll
      for (int n = 0; n < 4; ++n)
        acc[m][n] = mfma_frag<CH>(av[m], bv[n], acc[m][n]);
    __builtin_amdgcn_s_setprio(0);
    __builtin_amdgcn_s_barrier();
    // ---- ph1: quad (m4-7, kk0), bv reused; issue t+1 A-kk0 ----
    #pragma unroll
    for (int m = 0; m < 4; ++m)
      av[m] = *reinterpret_cast<const s16x8*>(&lds[buf + ((wr * 8 + 4 + m) * 2 + 0) * 512 + lane8]);
    if (pf){
      #pragma unroll
      for (int l = 0; l < 2; ++l) gload16(PA + (size_t)(aoffE[l] + k1), &lds[nbuf + aldsE[l]]);
    }
    __builtin_amdgcn_s_barrier();
    __builtin_amdgcn_s_setprio(1);
    #pragma unroll
    for (int m = 0; m < 4; ++m)
      #pragma unroll
      for (int n = 0; n < 4; ++n)
        acc[4 + m][n] = mfma_frag<CH>(av[m], bv[n], acc[4 + m][n]);
    __builtin_amdgcn_s_setprio(0);
    if (pf) asm volatile("s_waitcnt vmcnt(4)" ::: "memory");
    else    asm volatile("s_waitcnt vmcnt(0)" ::: "memory");
    __builtin_amdgcn_s_barrier();
    __builtin_amdgcn_sched_barrier(0);
    // ---- ph2: quad (m0-3, kk1); issue t+1 B-kk1 ----
    #pragma unroll
    for (int m = 0; m < 4; ++m)
      av[m] = *reinterpret_cast<const s16x8*>(&lds[buf + ((wr * 8 + m) * 2 + 1) * 512 + lane8]);
    #pragma unroll
    for (int n = 0; n < 4; ++n)
      bv[n] = *reinterpret_cast<const s16x8*>(&lds[buf + 16384 + ((wc * 4 + n) * 2 + 1) * 512 + lane8]);
    if (pf){
      #pragma unroll
      for (int l = 0; l < 2; ++l) gload16(PB + (size_t)(boffE[l] + k1 + 32), &lds[nbuf + bldsE[l] + 512]);
    }
    __builtin_amdgcn_s_barrier();
    __builtin_amdgcn_s_setprio(1);
    #pragma unroll
    for (int m = 0; m < 4; ++m)
      #pragma unroll
      for (int n = 0; n < 4; ++n)
        acc[m][n] = mfma_frag<CH>(av[m], bv[n], acc[m][n]);
    __builtin_amdgcn_s_setprio(0);
    __builtin_amdgcn_s_barrier();
    // ---- ph3: quad (m4-7, kk1), bv reused; issue t+1 A-kk1 ----
    #pragma unroll
    for (int m = 0; m < 4; ++m)
      av[m] = *reinterpret_cast<const s16x8*>(&lds[buf + ((wr * 8 + 4 + m) * 2 + 1) * 512 + lane8]);
    if (pf){
      #pragma unroll
      for (int l = 0; l < 2; ++l) gload16(PA + (size_t)(aoffE[l] + k1 + 32), &lds[nbuf + aldsE[l] + 512]);
    }
    __builtin_amdgcn_s_barrier();
    __builtin_amdgcn_s_setprio(1);
    #pragma unroll
    for (int m = 0; m < 4; ++m)
      #pragma unroll
      for (int n = 0; n < 4; ++n)
        acc[4 + m][n] = mfma_frag<CH>(av[m], bv[n], acc[4 + m][n]);
    __builtin_amdgcn_s_setprio(0);
    if (pf){
      asm volatile("s_waitcnt vmcnt(4)" ::: "memory");
      __builtin_amdgcn_s_barrier();
      __builtin_amdgcn_sched_barrier(0);
    }
  }

  #pragma unroll
  for (int m = 0; m < 8; ++m){
    const int row0 = by * 256 + wr * 128 + m * 16 + kg * 4;
    #pragma unroll
    for (int n = 0; n < 4; ++n){
      const int col = bx * 256 + wc * 64 + n * 16 + cl;
      #pragma unroll
      for (int j = 0; j < 4; ++j){
        const size_t off = ((size_t)(row0 + j) + (size_t)bz * CBO) * 1024 + col;
        if (EPI == 0) C[off] = acc[m][n][j];
        else if (EPI == 1){
          const float v = acc[m][n][j];
          const short hh = f2bf(v);
          Ch[off] = hh; Cl[off] = f2bf(v - bf2f(hh));
        } else if (EPI == 2){
          const float v = acc[m][n][j];
          const _Float16 hh = (_Float16)v;
          Ch[off] = __builtin_bit_cast(short, hh);
          const _Float16 ll = (_Float16)(v - (float)hh);
          Cl[off] = __builtin_bit_cast(short, ll);
        } else {
          Ch[off] = f2h(acc[m][n][j]);
        }
      }
    }
  }
}

// K3: in-place row softmax of (logits + mask[b][s]); fp16 copy for K4
__global__ __launch_bounds__(256) void k3_softmax(float* __restrict__ logits,
                                                  const float* __restrict__ mask,
                                                  short* __restrict__ sbf){
  const int row = blockIdx.x;       // b*TQ + t
  const int b = row >> 10;
  const int tid = threadIdx.x;
  float* p = logits + (size_t)row * DIM;
  f32x4 v  = *reinterpret_cast<const f32x4*>(p + tid * 4);
  f32x4 mk = *reinterpret_cast<const f32x4*>(mask + (size_t)b * DIM + tid * 4);
  v = v + mk;
  float mx = fmaxf(fmaxf(v[0], v[1]), fmaxf(v[2], v[3]));
  #pragma unroll
  for (int off = 32; off; off >>= 1) mx = fmaxf(mx, __shfl_xor(mx, off));
  __shared__ float red[8];
  const int lane = tid & 63, wid = tid >> 6;
  if (lane == 0) red[wid] = mx;
  __syncthreads();
  mx = fmaxf(fmaxf(red[0], red[1]), fmaxf(red[2], red[3]));
  f32x4 e;
  #pragma unroll
  for (int j = 0; j < 4; ++j) e[j] = __expf(v[j] - mx);
  float s = e[0] + e[1] + e[2] + e[3];
  #pragma unroll
  for (int off = 32; off; off >>= 1) s += __shfl_xor(s, off);
  if (lane == 0) red[4 + wid] = s;
  __syncthreads();
  s = red[4] + red[5] + red[6] + red[7];
  const float inv = 1.0f / s;
  f32x4 o;
  s16x4 ob;
  #pragma unroll
  for (int j = 0; j < 4; ++j){ o[j] = e[j] * inv; ob[j] = f2h(o[j]); }
  *reinterpret_cast<f32x4*>(p + tid * 4) = o;
  if (sbf) *reinterpret_cast<s16x4*>(sbf + (size_t)row * DIM + tid * 4) = ob;
}

// ---------------- fallback (round-3 passing) kernels ----------------

__global__ __launch_bounds__(256) void k1_qp(const float* __restrict__ A,
                                             const float* __restrict__ Wm,
                                             float* __restrict__ C){
  __shared__ __align__(16) short Ah[BM * STR];
  __shared__ __align__(16) short Al[BM * STR];
  __shared__ __align__(16) short Bh[BN * STR];
  __shared__ __align__(16) short Bl[BN * STR];
  const int tid = threadIdx.x;
  const int m0 = blockIdx.y * BM, n0 = blockIdx.x * BN;
  const int lane = tid & 63, wid = tid >> 6;
  const int wm = (wid >> 1) * 64, wn = (wid & 1) * 64;
  const int cl = lane & 15, kg = lane >> 4;
  const int rr = tid >> 3, f4 = (tid & 7) * 4;
  f32x4 acc[4][4] = {};
  for (int k0 = 0; k0 < DIM; k0 += BK){
    #pragma unroll
    for (int i = 0; i < 4; ++i){
      const int r = rr + i * 32;
      f32x4 va = *reinterpret_cast<const f32x4*>(A  + (size_t)(m0 + r) * DIM + k0 + f4);
      f32x4 vb = *reinterpret_cast<const f32x4*>(Wm + (size_t)(n0 + r) * DIM + k0 + f4);
      s16x4 ha, la, hb, lb;
      #pragma unroll
      for (int j = 0; j < 4; ++j){
        ha[j] = f2bf(va[j]); la[j] = f2bf(va[j] - bf2f(ha[j]));
        hb[j] = f2bf(vb[j]); lb[j] = f2bf(vb[j] - bf2f(hb[j]));
      }
      *reinterpret_cast<s16x4*>(&Ah[r * STR + f4]) = ha;
      *reinterpret_cast<s16x4*>(&Al[r * STR + f4]) = la;
      *reinterpret_cast<s16x4*>(&Bh[r * STR + f4]) = hb;
      *reinterpret_cast<s16x4*>(&Bl[r * STR + f4]) = lb;
    }
    __syncthreads();
    s16x8 ah[4], al8[4], bh8[4], bl8[4];
    #pragma unroll
    for (int m = 0; m < 4; ++m){
      ah[m]  = *reinterpret_cast<const s16x8*>(&Ah[(wm + m * 16 + cl) * STR + kg * 8]);
      al8[m] = *reinterpret_cast<const s16x8*>(&Al[(wm + m * 16 + cl) * STR + kg * 8]);
    }
    #pragma unroll
    for (int n = 0; n < 4; ++n){
      bh8[n] = *reinterpret_cast<const s16x8*>(&Bh[(wn + n * 16 + cl) * STR + kg * 8]);
      bl8[n] = *reinterpret_cast<const s16x8*>(&Bl[(wn + n * 16 + cl) * STR + kg * 8]);
    }
    #pragma unroll
    for (int m = 0; m < 4; ++m)
      #pragma unroll
      for (int n = 0; n < 4; ++n){
        acc[m][n] = __builtin_amdgcn_mfma_f32_16x16x32_bf16(ah[m],  bh8[n], acc[m][n], 0, 0, 0);
        acc[m][n] = __builtin_amdgcn_mfma_f32_16x16x32_bf16(al8[m], bh8[n], acc[m][n], 0, 0, 0);
        acc[m][n] = __builtin_amdgcn_mfma_f32_16x16x32_bf16(ah[m],  bl8[n], acc[m][n], 0, 0, 0);
      }
    __syncthreads();
  }
  #pragma unroll
  for (int m = 0; m < 4; ++m){
    const int row = m0 + wm + m * 16 + kg * 4;
    #pragma unroll
    for (int n = 0; n < 4; ++n){
      const int col = n0 + wn + n * 16 + cl;
      #pragma unroll
      for (int j = 0; j < 4; ++j)
        C[(size_t)(row + j) * DIM + col] = acc[m][n][j];
    }
  }
}

__global__ __launch_bounds__(256) void k2_logits(const float* __restrict__ qp,
                                                 const float* __restrict__ keys,
                                                 float* __restrict__ out){
  __shared__ __align__(16) short Ah[BM * STR];
  __shared__ __align__(16) short Al[BM * STR];
  __shared__ __align__(16) short Bh[BN * STR];
  __shared__ __align__(16) short Bl[BN * STR];
  const int tid = threadIdx.x;
  const int b = blockIdx.z;
  const int t0 = blockIdx.y * BM, s0 = blockIdx.x * BN;
  const int lane = tid & 63, wid = tid >> 6;
  const int wm = (wid >> 1) * 64, wn = (wid & 1) * 64;
  const int cl = lane & 15, kg = lane >> 4;
  const int rr = tid >> 3, f4 = (tid & 7) * 4;
  f32x4 acc[4][4] = {};
  for (int k0 = 0; k0 < DIM; k0 += BK){
    #pragma unroll
    for (int i = 0; i < 4; ++i){
      const int r = rr + i * 32;
      f32x4 va = *reinterpret_cast<const f32x4*>(qp   + (size_t)((t0 + r) * NB + b) * DIM + k0 + f4);
      f32x4 vb = *reinterpret_cast<const f32x4*>(keys + ((size_t)b * DIM + s0 + r) * DIM + k0 + f4);
      s16x4 ha, la, hb, lb;
      #pragma unroll
      for (int j = 0; j < 4; ++j){
        ha[j] = f2bf(va[j]); la[j] = f2bf(va[j] - bf2f(ha[j]));
        hb[j] = f2bf(vb[j]); lb[j] = f2bf(vb[j] - bf2f(hb[j]));
      }
      *reinterpret_cast<s16x4*>(&Ah[r * STR + f4]) = ha;
      *reinterpret_cast<s16x4*>(&Al[r * STR + f4]) = la;
      *reinterpret_cast<s16x4*>(&Bh[r * STR + f4]) = hb;
      *reinterpret_cast<s16x4*>(&Bl[r * STR + f4]) = lb;
    }
    __syncthreads();
    s16x8 ah[4], al8[4], bh8[4], bl8[4];
    #pragma unroll
    for (int m = 0; m < 4; ++m){
      ah[m]  = *reinterpret_cast<const s16x8*>(&Ah[(wm + m * 16 + cl) * STR + kg * 8]);
      al8[m] = *reinterpret_cast<const s16x8*>(&Al[(wm + m * 16 + cl) * STR + kg * 8]);
    }
    #pragma unroll
    for (int n = 0; n < 4; ++n){
      bh8[n] = *reinterpret_cast<const s16x8*>(&Bh[(wn + n * 16 + cl) * STR + kg * 8]);
      bl8[n] = *reinterpret_cast<const s16x8*>(&Bl[(wn + n * 16 + cl) * STR + kg * 8]);
    }
    #pragma unroll
    for (int m = 0; m < 4; ++m)
      #pragma unroll
      for (int n = 0; n < 4; ++n){
        acc[m][n] = __builtin_amdgcn_mfma_f32_16x16x32_bf16(ah[m],  bh8[n], acc[m][n], 0, 0, 0);
        acc[m][n] = __builtin_amdgcn_mfma_f32_16x16x32_bf16(al8[m], bh8[n], acc[m][n], 0, 0, 0);
        acc[m][n] = __builtin_amdgcn_mfma_f32_16x16x32_bf16(ah[m],  bl8[n], acc[m][n], 0, 0, 0);
      }
    __syncthreads();
  }
  #pragma unroll
  for (int m = 0; m < 4; ++m){
    const int trow = t0 + wm + m * 16 + kg * 4;
    #pragma unroll
    for (int n = 0; n < 4; ++n){
      const int scol = s0 + wn + n * 16 + cl;
      #pragma unroll
      for (int j = 0; j < 4; ++j)
        out[((size_t)b * TQn + trow + j) * DIM + scol] = acc[m][n][j];
    }
  }
}

__global__ __launch_bounds__(256) void k4_ctx(const float* __restrict__ score,
                                              const float* __restrict__ values,
                                              float* __restrict__ ctx){
  __shared__ __align__(16) short As[BM * STR];
  __shared__ __align__(16) float Vs[BK * VSTR];
  const int tid = threadIdx.x;
  const int b = blockIdx.z;
  const int t0 = blockIdx.y * BM, v0 = blockIdx.x * BN;
  const int lane = tid & 63, wid = tid >> 6;
  const int wm = (wid >> 1) * 64, wn = (wid & 1) * 64;
  const int cl = lane & 15, kg = lane >> 4;
  const int rr = tid >> 3, f4 = (tid & 7) * 4;
  const int vr = tid >> 5, vc = tid & 31;
  f32x4 acc[4][4] = {};
  for (int k0 = 0; k0 < DIM; k0 += BK){
    #pragma unroll
    for (int i = 0; i < 4; ++i){
      const int r = rr + i * 32;
      f32x4 va = *reinterpret_cast<const f32x4*>(score + ((size_t)b * TQn + t0 + r) * DIM + k0 + f4);
      s16x4 ha;
      #pragma unroll
      for (int j = 0; j < 4; ++j) ha[j] = f2bf(va[j]);
      *reinterpret_cast<s16x4*>(&As[r * STR + f4]) = ha;
      const int vrow = vr + i * 8;
      f32x4 vv = *reinterpret_cast<const f32x4*>(values + ((size_t)b * DIM + k0 + vrow) * DIM + v0 + vc * 4);
      const int cb = vc ^ (((vrow >> 3) & 1) << 2);
      *reinterpret_cast<f32x4*>(&Vs[vrow * VSTR + cb * 4]) = vv;
    }
    __syncthreads();
    s16x8 af[4], bfr[4];
    #pragma unroll
    for (int m = 0; m < 4; ++m)
      af[m] = *reinterpret_cast<const s16x8*>(&As[(wm + m * 16 + cl) * STR + kg * 8]);
    #pragma unroll
    for (int n = 0; n < 4; ++n){
      const int colb = wn + n * 16 + cl;
      const int cb = (colb >> 2) ^ ((kg & 1) << 2);
      #pragma unroll
      for (int j = 0; j < 8; ++j){
        const int rowv = kg * 8 + j;
        bfr[n][j] = f2bf(Vs[rowv * VSTR + cb * 4 + (colb & 3)]);
      }
    }
    #pragma unroll
    for (int m = 0; m < 4; ++m)
      #pragma unroll
      for (int n = 0; n < 4; ++n)
        acc[m][n] = __builtin_amdgcn_mfma_f32_16x16x32_bf16(af[m], bfr[n], acc[m][n], 0, 0, 0);
    __syncthreads();
  }
  #pragma unroll
  for (int m = 0; m < 4; ++m){
    const int trow = t0 + wm + m * 16 + kg * 4;
    #pragma unroll
    for (int n = 0; n < 4; ++n){
      const int vcol = v0 + wn + n * 16 + cl;
      #pragma unroll
      for (int j = 0; j < 4; ++j)
        ctx[((size_t)b * TQn + trow + j) * DIM + vcol] = acc[m][n][j];
    }
  }
}

extern "C" void kernel_launch(void* const* d_in, const int* in_sizes, int n_in,
                              void* d_out, int out_size, void* d_ws, size_t ws_size,
                              hipStream_t stream){
  (void)in_sizes; (void)n_in; (void)out_size;
  const float* query  = (const float*)d_in[0];  // [1024][16][1024] == m-major [16384][1024]
  const float* keys   = (const float*)d_in[1];  // [16][1024][1024]
  const float* values = (const float*)d_in[2];  // [16][1024][1024]
  const float* mask   = (const float*)d_in[3];  // [16][1024]
  const float* Wm     = (const float*)d_in[4];  // [1024][1024]
  float* score = (float*)d_out;                              // [16][1024][1024]
  float* ctx   = score + (size_t)NB * TQn * DIM;             // qp-plane scratch then real ctx
  dim3 blk(256, 1, 1);
  dim3 blk512(512, 1, 1);

  const size_t M16 = (size_t)16 * 1024 * 1024;   // 16M shorts
  const size_t M1  = (size_t)1024 * 1024;
  const size_t need = (4 * M16 + M1) * 2;        // 130 MB
  if (ws_size >= need){
    short* w  = (short*)d_ws;
    short* qf = w;                 // query fp16 (single plane)
    short* kf = qf + M16;          // keys fp16 (single plane)
    short* wf = kf + M16;          // W fp16 (single plane)
    short* vT = wf + M1;           // values^T fp16 [b][v][s]
    short* sb = vT + M16;          // score fp16
    short* qph = (short*)ctx;      // qp fp16 single plane (m-major [16384][1024])

    // merged k0: cvt(query,keys,W) + transpose(values) in one dispatch
    k0_all<<<dim3(37888, 1, 1), blk, 0, stream>>>(query, keys, Wm, values,
                                                  qf, kf, wf, vT);
    // K1: qp = qf . wf^T  (fp16 1-chain) -> fp16 single plane, A-panel-grouped swizzle
    gemm256<4, 3, 2><<<dim3(4, 64, 1), blk512, 0, stream>>>(qf, nullptr, wf, nullptr,
        nullptr, qph, nullptr, 1, 0, 1, 0, 0);
    // K2: logits = qph . kf  (fp16 1-chain), bz-per-XCD swizzle
    gemm256<4, 0, 1><<<dim3(4, 4, 16), blk512, 0, stream>>>(qph, nullptr, kf, nullptr,
        score, nullptr, nullptr, 16, 1, 1, 1024, 1024);
    k3_softmax<<<dim3(NB * TQn, 1, 1), blk, 0, stream>>>(score, mask, sb);
    // K4: ctx = sb . vT  (fp16 1-chain), bz-per-XCD swizzle
    gemm256<4, 0, 1><<<dim3(4, 4, 16), blk512, 0, stream>>>(sb, nullptr, vT, nullptr,
        ctx, nullptr, nullptr, 1, 1024, 1, 1024, 1024);
  } else {
    k1_qp<<<dim3(DIM / BN, (TQn * NB) / BM, 1), blk, 0, stream>>>(query, Wm, ctx);
    k2_logits<<<dim3(DIM / BN, TQn / BM, NB), blk, 0, stream>>>(ctx, keys, score);
    k3_softmax<<<dim3(NB * TQn, 1, 1), blk, 0, stream>>>(score, mask, nullptr);
    k4_ctx<<<dim3(DIM / BN, TQn / BM, NB), blk, 0, stream>>>(score, values, ctx);
  }
}

// Round 17
// 216.036 us; speedup vs baseline: 1.1595x; 1.0457x over previous
//
#include <hip/hip_runtime.h>
#include <hip/hip_bf16.h>

#define TQn 1024
#define NB  16
#define DIM 1024
#define BM  128
#define BN  128
#define BK  32
#define STR 40
#define VSTR 132

typedef __attribute__((ext_vector_type(4))) float f32x4;
typedef __attribute__((ext_vector_type(8))) short s16x8;
typedef __attribute__((ext_vector_type(4))) short s16x4;
typedef __attribute__((ext_vector_type(4))) unsigned u32x4;
typedef __attribute__((ext_vector_type(8))) _Float16 h16x8;

__device__ __forceinline__ short f2bf(float f){
  union { float f; unsigned u; } v; v.f = f;
  unsigned r = v.u + 0x7fffu + ((v.u >> 16) & 1u);  // RNE
  return (short)(r >> 16);
}
__device__ __forceinline__ float bf2f(short h){
  union { unsigned u; float f; } v; v.u = ((unsigned)(unsigned short)h) << 16;
  return v.f;
}
__device__ __forceinline__ short f2h(float f){
  _Float16 h = (_Float16)f;
  return __builtin_bit_cast(short, h);
}
__device__ __forceinline__ unsigned packh(float lo, float hi){
  return (unsigned)(unsigned short)f2h(lo) | ((unsigned)(unsigned short)f2h(hi) << 16);
}

__device__ __forceinline__ void gload16(const short* g, short* l){
#if __has_builtin(__builtin_amdgcn_global_load_lds)
  __builtin_amdgcn_global_load_lds(
      (const __attribute__((address_space(1))) unsigned int*)(const void*)g,
      (__attribute__((address_space(3))) unsigned int*)(void*)l, 16, 0, 0);
#else
  *reinterpret_cast<s16x8*>(l) = *reinterpret_cast<const s16x8*>(g);
#endif
}

template<int CH>
__device__ __forceinline__ f32x4 mfma_frag(s16x8 a, s16x8 b, f32x4 c){
  if constexpr (CH == 2 || CH == 4)
    return __builtin_amdgcn_mfma_f32_16x16x32_f16(
        __builtin_bit_cast(h16x8, a), __builtin_bit_cast(h16x8, b), c, 0, 0, 0);
  else
    return __builtin_amdgcn_mfma_f32_16x16x32_bf16(a, b, c, 0, 0, 0);
}

// ---------------- fast path ----------------

// merged k0: blocks [0,4096) transpose values [b][s][v] fp32 -> vT [b][v][s] fp16
// (dword-packed pad-35 LDS: conflict-free writes/reads); blocks [4096,37888)
// convert query/keys/W fp32 -> fp16 planes (pure streaming tail).
__global__ __launch_bounds__(256) void k0_all(const float* __restrict__ q,
                                              const float* __restrict__ k,
                                              const float* __restrict__ wm,
                                              const float* __restrict__ vals,
                                              short* __restrict__ qf,
                                              short* __restrict__ kf,
                                              short* __restrict__ wf,
                                              short* __restrict__ vT){
  __shared__ unsigned D[64 * 35];   // 8960 B
  const int bid = blockIdx.x;
  const int t = threadIdx.x;
  if (bid < 4096){
    const int v0 = (bid & 15) * 64;
    const int s0 = ((bid >> 4) & 15) * 64;
    const int b  = bid >> 8;
    // phase A: pair p = t>>3 (s rows 2p,2p+1), vg = t&7 (v block of 8)
    const int p = t >> 3, vg = t & 7;
    const float* r0 = vals + ((size_t)b * TQn + s0 + 2 * p) * DIM + v0 + vg * 8;
    const float* r1 = r0 + DIM;
    f32x4 r0a = *reinterpret_cast<const f32x4*>(r0);
    f32x4 r0b = *reinterpret_cast<const f32x4*>(r0 + 4);
    f32x4 r1a = *reinterpret_cast<const f32x4*>(r1);
    f32x4 r1b = *reinterpret_cast<const f32x4*>(r1 + 4);
    #pragma unroll
    for (int e = 0; e < 4; ++e)
      D[(vg * 8 + e) * 35 + p] = packh(r0a[e], r1a[e]);
    #pragma unroll
    for (int e = 0; e < 4; ++e)
      D[(vg * 8 + 4 + e) * 35 + p] = packh(r0b[e], r1b[e]);
    __syncthreads();
    // phase B: v = t>>2, q = t&3 -> s chunk q*16..+15 (8 dwords)
    const int v = t >> 2, qq = t & 3;
    u32x4 d0, d1;
    #pragma unroll
    for (int j = 0; j < 4; ++j) d0[j] = D[v * 35 + qq * 8 + j];
    #pragma unroll
    for (int j = 0; j < 4; ++j) d1[j] = D[v * 35 + qq * 8 + 4 + j];
    short* dst = vT + ((size_t)b * DIM + v0 + v) * TQn + s0 + qq * 16;
    *reinterpret_cast<u32x4*>(dst)     = d0;
    *reinterpret_cast<u32x4*>(dst + 8) = d1;
  } else {
    const size_t NQ = (size_t)16 * 1024 * 1024;
    const size_t i = ((size_t)(bid - 4096) * 256 + t) * 4;
    const float* in; short* out; size_t off;
    if (i < NQ){ in = q; out = qf; off = i; }
    else if (i < 2 * NQ){ in = k; out = kf; off = i - NQ; }
    else { in = wm; out = wf; off = i - 2 * NQ; }
    f32x4 v = *reinterpret_cast<const f32x4*>(in + off);
    s16x4 o;
    #pragma unroll
    for (int j = 0; j < 4; ++j) o[j] = f2h(v[j]);
    *reinterpret_cast<s16x4*>(out + off) = o;
  }
}

// 256x256 A*B^T GEMM, 8 waves (2Mx4N), BK=64, dbuf 128KB, fragment-major
// (conflict-free b128), r12 counted-vmcnt 4-phase pipeline + XCD swizzle (T1).
template<int CH, int EPI, int SWZ>
__global__ __launch_bounds__(512, 2) void gemm256(
    const short* __restrict__ Ah, const short* __restrict__ Al,
    const short* __restrict__ Bh, const short* __restrict__ Bl,
    float* __restrict__ C, short* __restrict__ Ch, short* __restrict__ Cl,
    int ARS, int ABO, int BRS, int BBO, int CBO)
{
  constexpr int NSTEP = (CH == 3) ? 48 : (CH == 2) ? 32 : 16;
  __shared__ __align__(16) short lds[2 * 32768];   // 128 KB
  const int tid = threadIdx.x;
  const int lane = tid & 63, w = tid >> 6;
  const int cl = lane & 15, kg = lane >> 4;
  const int lane8 = lane * 8;
  int bx, by, bz;
  if (SWZ == 1){
    const int lin = blockIdx.x + 4 * (blockIdx.y + 4 * blockIdx.z);  // 0..255
    const int xcd = lin & 7, idx = lin >> 3;
    bz = 2 * xcd + (idx >> 4);
    const int rem = idx & 15;
    by = rem >> 2; bx = rem & 3;
  } else if (SWZ == 2){
    const int lin = blockIdx.x + 4 * blockIdx.y;
    const int xcd = lin & 7, idx = lin >> 3;
    by = xcd * 8 + (idx >> 2); bx = idx & 3; bz = 0;
  } else {
    bx = blockIdx.x; by = blockIdx.y; bz = blockIdx.z;
  }
  const int wr = w >> 2, wc = w & 3;

  int aoffE[2], boffE[2], aldsE[2], bldsE[2];
  #pragma unroll
  for (int l = 0; l < 2; ++l){
    const int rg = 2 * w + l;
    const int arow = by * 256 + rg * 16 + cl;
    const int brow = bx * 256 + rg * 16 + cl;
    aoffE[l] = (arow * ARS + bz * ABO) * 1024 + kg * 8;
    boffE[l] = (brow * BRS + bz * BBO) * 1024 + kg * 8;
    aldsE[l] = (4 * w + 2 * l) * 512 + lane8;
    bldsE[l] = 16384 + (4 * w + 2 * l) * 512 + lane8;
  }

  f32x4 acc[8][4] = {};

  // prologue: stage tile 0 in deadline order; kk1 stays in flight.
  #pragma unroll
  for (int l = 0; l < 2; ++l) gload16(Bh + (size_t)boffE[l], &lds[bldsE[l]]);
  #pragma unroll
  for (int l = 0; l < 2; ++l) gload16(Ah + (size_t)aoffE[l], &lds[aldsE[l]]);
  #pragma unroll
  for (int l = 0; l < 2; ++l) gload16(Bh + (size_t)(boffE[l] + 32), &lds[bldsE[l] + 512]);
  #pragma unroll
  for (int l = 0; l < 2; ++l) gload16(Ah + (size_t)(aoffE[l] + 32), &lds[aldsE[l] + 512]);
  asm volatile("s_waitcnt vmcnt(4)" ::: "memory");
  __builtin_amdgcn_s_barrier();
  __builtin_amdgcn_sched_barrier(0);

  for (int t = 0; t < NSTEP; ++t){
    const int buf = (t & 1) * 32768;
    const int nbuf = buf ^ 32768;
    const bool pf = (t + 1 < NSTEP);
    int k1 = 0; const short *PA = Ah, *PB = Bh;
    if (pf){
      if (CH == 3){
        const int cc = (t + 1) % 3;
        k1 = ((t + 1) / 3) * 64;
        PA = (cc == 1) ? Al : Ah;
        PB = (cc == 2) ? Bl : Bh;
      } else if (CH == 2){
        k1 = ((t + 1) >> 1) * 64;
        PA = ((t + 1) & 1) ? Al : Ah;
        PB = Bh;
      } else k1 = (t + 1) * 64;
    }

    s16x8 av[4], bv[4];
    // ---- ph0: quad (m0-3, kk0); issue t+1 B-kk0 ----
    #pragma unroll
    for (int m = 0; m < 4; ++m)
      av[m] = *reinterpret_cast<const s16x8*>(&lds[buf + ((wr * 8 + m) * 2 + 0) * 512 + lane8]);
    #pragma unroll
    for (int n = 0; n < 4; ++n)
      bv[n] = *reinterpret_cast<const s16x8*>(&lds[buf + 16384 + ((wc * 4 + n) * 2 + 0) * 512 + lane8]);
    if (pf){
      #pragma unroll
      for (int l = 0; l < 2; ++l) gload16(PB + (size_t)(boffE[l] + k1), &lds[nbuf + bldsE[l]]);
    }
    __builtin_amdgcn_s_barrier();
    __builtin_amdgcn_s_setprio(1);
    #pragma unroll
    for (int m = 0; m < 4; ++m)
      #pragma unroll
      for (int n = 0; n < 4; ++n)
        acc[m][n] = mfma_frag<CH>(av[m], bv[n], acc[m][n]);
    __builtin_amdgcn_s_setprio(0);
    __builtin_amdgcn_s_barrier();
    // ---- ph1: quad (m4-7, kk0), bv reused; issue t+1 A-kk0 ----
    #pragma unroll
    for (int m = 0; m < 4; ++m)
      av[m] = *reinterpret_cast<const s16x8*>(&lds[buf + ((wr * 8 + 4 + m) * 2 + 0) * 512 + lane8]);
    if (pf){
      #pragma unroll
      for (int l = 0; l < 2; ++l) gload16(PA + (size_t)(aoffE[l] + k1), &lds[nbuf + aldsE[l]]);
    }
    __builtin_amdgcn_s_barrier();
    __builtin_amdgcn_s_setprio(1);
    #pragma unroll
    for (int m = 0; m < 4; ++m)
      #pragma unroll
      for (int n = 0; n < 4; ++n)
        acc[4 + m][n] = mfma_frag<CH>(av[m], bv[n], acc[4 + m][n]);
    __builtin_amdgcn_s_setprio(0);
    if (pf) asm volatile("s_waitcnt vmcnt(4)" ::: "memory");
    else    asm volatile("s_waitcnt vmcnt(0)" ::: "memory");
    __builtin_amdgcn_s_barrier();
    __builtin_amdgcn_sched_barrier(0);
    // ---- ph2: quad (m0-3, kk1); issue t+1 B-kk1 ----
    #pragma unroll
    for (int m = 0; m < 4; ++m)
      av[m] = *reinterpret_cast<const s16x8*>(&lds[buf + ((wr * 8 + m) * 2 + 1) * 512 + lane8]);
    #pragma unroll
    for (int n = 0; n < 4; ++n)
      bv[n] = *reinterpret_cast<const s16x8*>(&lds[buf + 16384 + ((wc * 4 + n) * 2 + 1) * 512 + lane8]);
    if (pf){
      #pragma unroll
      for (int l = 0; l < 2; ++l) gload16(PB + (size_t)(boffE[l] + k1 + 32), &lds[nbuf + bldsE[l] + 512]);
    }
    __builtin_amdgcn_s_barrier();
    __builtin_amdgcn_s_setprio(1);
    #pragma unroll
    for (int m = 0; m < 4; ++m)
      #pragma unroll
      for (int n = 0; n < 4; ++n)
        acc[m][n] = mfma_frag<CH>(av[m], bv[n], acc[m][n]);
    __builtin_amdgcn_s_setprio(0);
    __builtin_amdgcn_s_barrier();
    // ---- ph3: quad (m4-7, kk1), bv reused; issue t+1 A-kk1 ----
    #pragma unroll
    for (int m = 0; m < 4; ++m)
      av[m] = *reinterpret_cast<const s16x8*>(&lds[buf + ((wr * 8 + 4 + m) * 2 + 1) * 512 + lane8]);
    if (pf){
      #pragma unroll
      for (int l = 0; l < 2; ++l) gload16(PA + (size_t)(aoffE[l] + k1 + 32), &lds[nbuf + aldsE[l] + 512]);
    }
    __builtin_amdgcn_s_barrier();
    __builtin_amdgcn_s_setprio(1);
    #pragma unroll
    for (int m = 0; m < 4; ++m)
      #pragma unroll
      for (int n = 0; n < 4; ++n)
        acc[4 + m][n] = mfma_frag<CH>(av[m], bv[n], acc[4 + m][n]);
    __builtin_amdgcn_s_setprio(0);
    if (pf){
      asm volatile("s_waitcnt vmcnt(4)" ::: "memory");
      __builtin_amdgcn_s_barrier();
      __builtin_amdgcn_sched_barrier(0);
    }
  }

  #pragma unroll
  for (int m = 0; m < 8; ++m){
    const int row0 = by * 256 + wr * 128 + m * 16 + kg * 4;
    #pragma unroll
    for (int n = 0; n < 4; ++n){
      const int col = bx * 256 + wc * 64 + n * 16 + cl;
      #pragma unroll
      for (int j = 0; j < 4; ++j){
        const size_t off = ((size_t)(row0 + j) + (size_t)bz * CBO) * 1024 + col;
        if (EPI == 0) C[off] = acc[m][n][j];
        else if (EPI == 1){
          const float v = acc[m][n][j];
          const short hh = f2bf(v);
          Ch[off] = hh; Cl[off] = f2bf(v - bf2f(hh));
        } else if (EPI == 2){
          const float v = acc[m][n][j];
          const _Float16 hh = (_Float16)v;
          Ch[off] = __builtin_bit_cast(short, hh);
          const _Float16 ll = (_Float16)(v - (float)hh);
          Cl[off] = __builtin_bit_cast(short, ll);
        } else {
          Ch[off] = f2h(acc[m][n][j]);
        }
      }
    }
  }
}

// K3: in-place row softmax of (logits + mask[b][s]); fp16 copy for K4
__global__ __launch_bounds__(256) void k3_softmax(float* __restrict__ logits,
                                                  const float* __restrict__ mask,
                                                  short* __restrict__ sbf){
  const int row = blockIdx.x;       // b*TQ + t
  const int b = row >> 10;
  const int tid = threadIdx.x;
  float* p = logits + (size_t)row * DIM;
  f32x4 v  = *reinterpret_cast<const f32x4*>(p + tid * 4);
  f32x4 mk = *reinterpret_cast<const f32x4*>(mask + (size_t)b * DIM + tid * 4);
  v = v + mk;
  float mx = fmaxf(fmaxf(v[0], v[1]), fmaxf(v[2], v[3]));
  #pragma unroll
  for (int off = 32; off; off >>= 1) mx = fmaxf(mx, __shfl_xor(mx, off));
  __shared__ float red[8];
  const int lane = tid & 63, wid = tid >> 6;
  if (lane == 0) red[wid] = mx;
  __syncthreads();
  mx = fmaxf(fmaxf(red[0], red[1]), fmaxf(red[2], red[3]));
  f32x4 e;
  #pragma unroll
  for (int j = 0; j < 4; ++j) e[j] = __expf(v[j] - mx);
  float s = e[0] + e[1] + e[2] + e[3];
  #pragma unroll
  for (int off = 32; off; off >>= 1) s += __shfl_xor(s, off);
  if (lane == 0) red[4 + wid] = s;
  __syncthreads();
  s = red[4] + red[5] + red[6] + red[7];
  const float inv = 1.0f / s;
  f32x4 o;
  s16x4 ob;
  #pragma unroll
  for (int j = 0; j < 4; ++j){ o[j] = e[j] * inv; ob[j] = f2h(o[j]); }
  *reinterpret_cast<f32x4*>(p + tid * 4) = o;
  if (sbf) *reinterpret_cast<s16x4*>(sbf + (size_t)row * DIM + tid * 4) = ob;
}

// ---------------- fallback (round-3 passing) kernels ----------------

__global__ __launch_bounds__(256) void k1_qp(const float* __restrict__ A,
                                             const float* __restrict__ Wm,
                                             float* __restrict__ C){
  __shared__ __align__(16) short Ah[BM * STR];
  __shared__ __align__(16) short Al[BM * STR];
  __shared__ __align__(16) short Bh[BN * STR];
  __shared__ __align__(16) short Bl[BN * STR];
  const int tid = threadIdx.x;
  const int m0 = blockIdx.y * BM, n0 = blockIdx.x * BN;
  const int lane = tid & 63, wid = tid >> 6;
  const int wm = (wid >> 1) * 64, wn = (wid & 1) * 64;
  const int cl = lane & 15, kg = lane >> 4;
  const int rr = tid >> 3, f4 = (tid & 7) * 4;
  f32x4 acc[4][4] = {};
  for (int k0 = 0; k0 < DIM; k0 += BK){
    #pragma unroll
    for (int i = 0; i < 4; ++i){
      const int r = rr + i * 32;
      f32x4 va = *reinterpret_cast<const f32x4*>(A  + (size_t)(m0 + r) * DIM + k0 + f4);
      f32x4 vb = *reinterpret_cast<const f32x4*>(Wm + (size_t)(n0 + r) * DIM + k0 + f4);
      s16x4 ha, la, hb, lb;
      #pragma unroll
      for (int j = 0; j < 4; ++j){
        ha[j] = f2bf(va[j]); la[j] = f2bf(va[j] - bf2f(ha[j]));
        hb[j] = f2bf(vb[j]); lb[j] = f2bf(vb[j] - bf2f(hb[j]));
      }
      *reinterpret_cast<s16x4*>(&Ah[r * STR + f4]) = ha;
      *reinterpret_cast<s16x4*>(&Al[r * STR + f4]) = la;
      *reinterpret_cast<s16x4*>(&Bh[r * STR + f4]) = hb;
      *reinterpret_cast<s16x4*>(&Bl[r * STR + f4]) = lb;
    }
    __syncthreads();
    s16x8 ah[4], al8[4], bh8[4], bl8[4];
    #pragma unroll
    for (int m = 0; m < 4; ++m){
      ah[m]  = *reinterpret_cast<const s16x8*>(&Ah[(wm + m * 16 + cl) * STR + kg * 8]);
      al8[m] = *reinterpret_cast<const s16x8*>(&Al[(wm + m * 16 + cl) * STR + kg * 8]);
    }
    #pragma unroll
    for (int n = 0; n < 4; ++n){
      bh8[n] = *reinterpret_cast<const s16x8*>(&Bh[(wn + n * 16 + cl) * STR + kg * 8]);
      bl8[n] = *reinterpret_cast<const s16x8*>(&Bl[(wn + n * 16 + cl) * STR + kg * 8]);
    }
    #pragma unroll
    for (int m = 0; m < 4; ++m)
      #pragma unroll
      for (int n = 0; n < 4; ++n){
        acc[m][n] = __builtin_amdgcn_mfma_f32_16x16x32_bf16(ah[m],  bh8[n], acc[m][n], 0, 0, 0);
        acc[m][n] = __builtin_amdgcn_mfma_f32_16x16x32_bf16(al8[m], bh8[n], acc[m][n], 0, 0, 0);
        acc[m][n] = __builtin_amdgcn_mfma_f32_16x16x32_bf16(ah[m],  bl8[n], acc[m][n], 0, 0, 0);
      }
    __syncthreads();
  }
  #pragma unroll
  for (int m = 0; m < 4; ++m){
    const int row = m0 + wm + m * 16 + kg * 4;
    #pragma unroll
    for (int n = 0; n < 4; ++n){
      const int col = n0 + wn + n * 16 + cl;
      #pragma unroll
      for (int j = 0; j < 4; ++j)
        C[(size_t)(row + j) * DIM + col] = acc[m][n][j];
    }
  }
}

__global__ __launch_bounds__(256) void k2_logits(const float* __restrict__ qp,
                                                 const float* __restrict__ keys,
                                                 float* __restrict__ out){
  __shared__ __align__(16) short Ah[BM * STR];
  __shared__ __align__(16) short Al[BM * STR];
  __shared__ __align__(16) short Bh[BN * STR];
  __shared__ __align__(16) short Bl[BN * STR];
  const int tid = threadIdx.x;
  const int b = blockIdx.z;
  const int t0 = blockIdx.y * BM, s0 = blockIdx.x * BN;
  const int lane = tid & 63, wid = tid >> 6;
  const int wm = (wid >> 1) * 64, wn = (wid & 1) * 64;
  const int cl = lane & 15, kg = lane >> 4;
  const int rr = tid >> 3, f4 = (tid & 7) * 4;
  f32x4 acc[4][4] = {};
  for (int k0 = 0; k0 < DIM; k0 += BK){
    #pragma unroll
    for (int i = 0; i < 4; ++i){
      const int r = rr + i * 32;
      f32x4 va = *reinterpret_cast<const f32x4*>(qp   + (size_t)((t0 + r) * NB + b) * DIM + k0 + f4);
      f32x4 vb = *reinterpret_cast<const f32x4*>(keys + ((size_t)b * DIM + s0 + r) * DIM + k0 + f4);
      s16x4 ha, la, hb, lb;
      #pragma unroll
      for (int j = 0; j < 4; ++j){
        ha[j] = f2bf(va[j]); la[j] = f2bf(va[j] - bf2f(ha[j]));
        hb[j] = f2bf(vb[j]); lb[j] = f2bf(vb[j] - bf2f(hb[j]));
      }
      *reinterpret_cast<s16x4*>(&Ah[r * STR + f4]) = ha;
      *reinterpret_cast<s16x4*>(&Al[r * STR + f4]) = la;
      *reinterpret_cast<s16x4*>(&Bh[r * STR + f4]) = hb;
      *reinterpret_cast<s16x4*>(&Bl[r * STR + f4]) = lb;
    }
    __syncthreads();
    s16x8 ah[4], al8[4], bh8[4], bl8[4];
    #pragma unroll
    for (int m = 0; m < 4; ++m){
      ah[m]  = *reinterpret_cast<const s16x8*>(&Ah[(wm + m * 16 + cl) * STR + kg * 8]);
      al8[m] = *reinterpret_cast<const s16x8*>(&Al[(wm + m * 16 + cl) * STR + kg * 8]);
    }
    #pragma unroll
    for (int n = 0; n < 4; ++n){
      bh8[n] = *reinterpret_cast<const s16x8*>(&Bh[(wn + n * 16 + cl) * STR + kg * 8]);
      bl8[n] = *reinterpret_cast<const s16x8*>(&Bl[(wn + n * 16 + cl) * STR + kg * 8]);
    }
    #pragma unroll
    for (int m = 0; m < 4; ++m)
      #pragma unroll
      for (int n = 0; n < 4; ++n){
        acc[m][n] = __builtin_amdgcn_mfma_f32_16x16x32_bf16(ah[m],  bh8[n], acc[m][n], 0, 0, 0);
        acc[m][n] = __builtin_amdgcn_mfma_f32_16x16x32_bf16(al8[m], bh8[n], acc[m][n], 0, 0, 0);
        acc[m][n] = __builtin_amdgcn_mfma_f32_16x16x32_bf16(ah[m],  bl8[n], acc[m][n], 0, 0, 0);
      }
    __syncthreads();
  }
  #pragma unroll
  for (int m = 0; m < 4; ++m){
    const int trow = t0 + wm + m * 16 + kg * 4;
    #pragma unroll
    for (int n = 0; n < 4; ++n){
      const int scol = s0 + wn + n * 16 + cl;
      #pragma unroll
      for (int j = 0; j < 4; ++j)
        out[((size_t)b * TQn + trow + j) * DIM + scol] = acc[m][n][j];
    }
  }
}

__global__ __launch_bounds__(256) void k4_ctx(const float* __restrict__ score,
                                              const float* __restrict__ values,
                                              float* __restrict__ ctx){
  __shared__ __align__(16) short As[BM * STR];
  __shared__ __align__(16) float Vs[BK * VSTR];
  const int tid = threadIdx.x;
  const int b = blockIdx.z;
  const int t0 = blockIdx.y * BM, v0 = blockIdx.x * BN;
  const int lane = tid & 63, wid = tid >> 6;
  const int wm = (wid >> 1) * 64, wn = (wid & 1) * 64;
  const int cl = lane & 15, kg = lane >> 4;
  const int rr = tid >> 3, f4 = (tid & 7) * 4;
  const int vr = tid >> 5, vc = tid & 31;
  f32x4 acc[4][4] = {};
  for (int k0 = 0; k0 < DIM; k0 += BK){
    #pragma unroll
    for (int i = 0; i < 4; ++i){
      const int r = rr + i * 32;
      f32x4 va = *reinterpret_cast<const f32x4*>(score + ((size_t)b * TQn + t0 + r) * DIM + k0 + f4);
      s16x4 ha;
      #pragma unroll
      for (int j = 0; j < 4; ++j) ha[j] = f2bf(va[j]);
      *reinterpret_cast<s16x4*>(&As[r * STR + f4]) = ha;
      const int vrow = vr + i * 8;
      f32x4 vv = *reinterpret_cast<const f32x4*>(values + ((size_t)b * DIM + k0 + vrow) * DIM + v0 + vc * 4);
      const int cb = vc ^ (((vrow >> 3) & 1) << 2);
      *reinterpret_cast<f32x4*>(&Vs[vrow * VSTR + cb * 4]) = vv;
    }
    __syncthreads();
    s16x8 af[4], bfr[4];
    #pragma unroll
    for (int m = 0; m < 4; ++m)
      af[m] = *reinterpret_cast<const s16x8*>(&As[(wm + m * 16 + cl) * STR + kg * 8]);
    #pragma unroll
    for (int n = 0; n < 4; ++n){
      const int colb = wn + n * 16 + cl;
      const int cb = (colb >> 2) ^ ((kg & 1) << 2);
      #pragma unroll
      for (int j = 0; j < 8; ++j){
        const int rowv = kg * 8 + j;
        bfr[n][j] = f2bf(Vs[rowv * VSTR + cb * 4 + (colb & 3)]);
      }
    }
    #pragma unroll
    for (int m = 0; m < 4; ++m)
      #pragma unroll
      for (int n = 0; n < 4; ++n)
        acc[m][n] = __builtin_amdgcn_mfma_f32_16x16x32_bf16(af[m], bfr[n], acc[m][n], 0, 0, 0);
    __syncthreads();
  }
  #pragma unroll
  for (int m = 0; m < 4; ++m){
    const int trow = t0 + wm + m * 16 + kg * 4;
    #pragma unroll
    for (int n = 0; n < 4; ++n){
      const int vcol = v0 + wn + n * 16 + cl;
      #pragma unroll
      for (int j = 0; j < 4; ++j)
        ctx[((size_t)b * TQn + trow + j) * DIM + vcol] = acc[m][n][j];
    }
  }
}

extern "C" void kernel_launch(void* const* d_in, const int* in_sizes, int n_in,
                              void* d_out, int out_size, void* d_ws, size_t ws_size,
                              hipStream_t stream){
  (void)in_sizes; (void)n_in; (void)out_size;
  const float* query  = (const float*)d_in[0];  // [1024][16][1024] == m-major [16384][1024]
  const float* keys   = (const float*)d_in[1];  // [16][1024][1024]
  const float* values = (const float*)d_in[2];  // [16][1024][1024]
  const float* mask   = (const float*)d_in[3];  // [16][1024]
  const float* Wm     = (const float*)d_in[4];  // [1024][1024]
  float* score = (float*)d_out;                              // [16][1024][1024]
  float* ctx   = score + (size_t)NB * TQn * DIM;             // qp-plane scratch then real ctx
  dim3 blk(256, 1, 1);
  dim3 blk512(512, 1, 1);

  const size_t M16 = (size_t)16 * 1024 * 1024;   // 16M shorts
  const size_t M1  = (size_t)1024 * 1024;
  const size_t need = (4 * M16 + M1) * 2;        // 130 MB
  if (ws_size >= need){
    short* w  = (short*)d_ws;
    short* qf = w;                 // query fp16 (single plane)
    short* kf = qf + M16;          // keys fp16 (single plane)
    short* wf = kf + M16;          // W fp16 (single plane)
    short* vT = wf + M1;           // values^T fp16 [b][v][s]
    short* sb = vT + M16;          // score fp16
    short* qph = (short*)ctx;      // qp fp16 single plane (m-major [16384][1024])

    // merged k0: vtrans blocks first (slow part starts early), cvt streams after
    k0_all<<<dim3(37888, 1, 1), blk, 0, stream>>>(query, keys, Wm, values,
                                                  qf, kf, wf, vT);
    // K1: qp = qf . wf^T  (fp16 1-chain) -> fp16 single plane, A-panel-grouped swizzle
    gemm256<4, 3, 2><<<dim3(4, 64, 1), blk512, 0, stream>>>(qf, nullptr, wf, nullptr,
        nullptr, qph, nullptr, 1, 0, 1, 0, 0);
    // K2: logits = qph . kf  (fp16 1-chain), bz-per-XCD swizzle
    gemm256<4, 0, 1><<<dim3(4, 4, 16), blk512, 0, stream>>>(qph, nullptr, kf, nullptr,
        score, nullptr, nullptr, 16, 1, 1, 1024, 1024);
    k3_softmax<<<dim3(NB * TQn, 1, 1), blk, 0, stream>>>(score, mask, sb);
    // K4: ctx = sb . vT  (fp16 1-chain), bz-per-XCD swizzle
    gemm256<4, 0, 1><<<dim3(4, 4, 16), blk512, 0, stream>>>(sb, nullptr, vT, nullptr,
        ctx, nullptr, nullptr, 1, 1024, 1, 1024, 1024);
  } else {
    k1_qp<<<dim3(DIM / BN, (TQn * NB) / BM, 1), blk, 0, stream>>>(query, Wm, ctx);
    k2_logits<<<dim3(DIM / BN, TQn / BM, NB), blk, 0, stream>>>(ctx, keys, score);
    k3_softmax<<<dim3(NB * TQn, 1, 1), blk, 0, stream>>>(score, mask, nullptr);
    k4_ctx<<<dim3(DIM / BN, TQn / BM, NB), blk, 0, stream>>>(score, values, ctx);
  }
}